// Round 4
// baseline (210.862 us; speedup 1.0000x reference)
//
#include <hip/hip_runtime.h>
#include <hip/hip_bf16.h>

#define LOG2E 1.4426950408889634f
// reference: mask(-1e9) BEFORE scale(/8); log2e folded into Q pre-scale
#define MASKVAL (-1.25e8f * LOG2E)

typedef __bf16 bf16x8 __attribute__((ext_vector_type(8)));
typedef __bf16 bf16x4 __attribute__((ext_vector_type(4)));
typedef short  shortx4 __attribute__((ext_vector_type(4)));
typedef float  floatx4 __attribute__((ext_vector_type(4)));

__device__ __forceinline__ floatx4 mfma16(bf16x8 a, bf16x8 b, floatx4 c) {
  return __builtin_amdgcn_mfma_f32_16x16x32_bf16(a, b, c, 0, 0, 0);
}

// 16x16x16 bf16 MFMA: B-operand layout (n=l15, k=quad*4+i) == S^T C-tile
// layout -> P feeds PV with zero cross-lane transforms.
__device__ __forceinline__ floatx4 mfma_pv(bf16x4 a, bf16x4 b, floatx4 c) {
#if __has_builtin(__builtin_amdgcn_mfma_f32_16x16x16_bf16)
  return __builtin_amdgcn_mfma_f32_16x16x16_bf16(a, b, c, 0, 0, 0);
#else
  shortx4 as, bs;
  __builtin_memcpy(&as, &a, 8);
  __builtin_memcpy(&bs, &b, 8);
  return __builtin_amdgcn_mfma_f32_16x16x16bf16_1k(as, bs, c, 0, 0, 0);
#endif
}

// async global->LDS, 16B per lane. Dest = wave-uniform base + lane*16.
__device__ __forceinline__ void load_lds16(const __bf16* g, __bf16* l) {
  __builtin_amdgcn_global_load_lds(
      (const __attribute__((address_space(1))) void*)g,
      (__attribute__((address_space(3))) void*)l, 16, 0, 0);
}

// ---------------------------------------------------------------------------
// Fold LoRA into weights, emit W_eff^T bf16 [ncols][1024].  Both weight sets
// in one launch: blockIdx.x < 48 -> qkv (ncols 3072), else proj (ncols 1024).
// ---------------------------------------------------------------------------
__global__ __launch_bounds__(256)
void fold_wt2(const float* __restrict__ Wq, const float* __restrict__ Aq,
              const float* __restrict__ Bq, __bf16* __restrict__ WTq,
              const float* __restrict__ Wp, const float* __restrict__ Ap,
              const float* __restrict__ Bp, __bf16* __restrict__ WTp) {
  __shared__ float tile[64][65];
  __shared__ float sLb[8][64];
  const int bx = blockIdx.x;
  const bool isQ = bx < 48;
  const float* W  = isQ ? Wq : Wp;
  const float* La = isQ ? Aq : Ap;
  const float* Lb = isQ ? Bq : Bp;
  __bf16* WT = isQ ? WTq : WTp;
  const int ncols = isQ ? 3072 : 1024;
  const int nt = (isQ ? bx : bx - 48) * 64;
  const int kt = blockIdx.y * 64;
  const int tid = threadIdx.x;
  const int tx = tid & 63, ty = tid >> 6;

  float rLa[8];
  *(float4*)&rLa[0] = *(const float4*)(La + (size_t)(kt + tx) * 8);
  *(float4*)&rLa[4] = *(const float4*)(La + (size_t)(kt + tx) * 8 + 4);

#pragma unroll
  for (int rep = 0; rep < 2; rep++) {
    int idx = tid + rep * 256;
    sLb[idx >> 6][idx & 63] = Lb[(size_t)(idx >> 6) * ncols + nt + (idx & 63)];
  }
#pragma unroll
  for (int rep = 0; rep < 16; rep++) {
    int i = rep * 4 + ty;
    tile[i][tx] = W[(size_t)(kt + i) * ncols + nt + tx];
  }
  __syncthreads();
#pragma unroll
  for (int rep = 0; rep < 16; rep++) {
    int i = rep * 4 + ty;
    int n = nt + i, k = kt + tx;
    float acc = tile[tx][i];
#pragma unroll
    for (int r = 0; r < 8; r++)
      acc += 2.0f * rLa[r] * sLb[r][i];  // LORA_SCALING = 2
    WT[(size_t)n * 1024 + k] = (__bf16)acc;
  }
}

__global__ __launch_bounds__(256)
void cast_x(const float* __restrict__ x, __bf16* __restrict__ o) {
  int i = blockIdx.x * 256 + threadIdx.x;
  float4 v = ((const float4*)x)[i];
  bf16x4 r = {(__bf16)v.x, (__bf16)v.y, (__bf16)v.z, (__bf16)v.w};
  ((bf16x4*)o)[i] = r;
}

// ---------------------------------------------------------------------------
// Fused QKV projection, swapped orientation: D[p][s] = sum_k WT[p][k] X[s][k].
// 128x128 tiles, BK=64, global_load_lds staging, XOR-swizzled LDS.
// Q channels (p<1024) pre-scaled by 0.125*LOG2E.
// V is written to vtb with keys PERMUTED within each 64-key chunk so the
// flash PV A-fragments are 16B-contiguous: key off (t=off>>4, qd=(off>>2)&3,
// r=off&3) stored at position (t>>1)*32 + qd*8 + (t&1)*4 + r.
// ---------------------------------------------------------------------------
__global__ __launch_bounds__(256)
void gemm_qkv(const __bf16* __restrict__ WT, const __bf16* __restrict__ X,
              const float* __restrict__ bias, __bf16* __restrict__ qk,
              __bf16* __restrict__ vtb) {
  const int K = 1024;
  __shared__ alignas(16) __bf16 As[128 * 64];
  __shared__ alignas(16) __bf16 Bs[128 * 64];
  const int tid = threadIdx.x;
  const int wave = tid >> 6, lane = tid & 63;
  const int wm = wave >> 1, wn = wave & 1;
  const int quad = lane >> 4, l15 = lane & 15;
  const int p0 = blockIdx.y * 128, s0 = blockIdx.x * 128;
  const int srow8 = lane >> 3, sc8 = lane & 7;
  const int sswz = sc8 ^ srow8;

  floatx4 acc[4][4] = {};

  for (int kb = 0; kb < K; kb += 64) {
    __syncthreads();
#pragma unroll
    for (int t = 0; t < 4; t++) {
      int rbase = (wave * 4 + t) * 8;
      int row = rbase + srow8;
      load_lds16(WT + (size_t)(p0 + row) * K + kb + sswz * 8, As + rbase * 64);
      load_lds16(X + (size_t)(s0 + row) * K + kb + sswz * 8, Bs + rbase * 64);
    }
    __syncthreads();
#pragma unroll
    for (int ks = 0; ks < 2; ks++) {
      bf16x8 af[4], bfv[4];
#pragma unroll
      for (int t = 0; t < 4; t++) {
        int ra = wm * 64 + t * 16 + l15;
        int rb = wn * 64 + t * 16 + l15;
        int ch = (ks * 4 + quad) ^ (l15 & 7);
        af[t]  = *(const bf16x8*)(As + ra * 64 + ch * 8);
        bfv[t] = *(const bf16x8*)(Bs + rb * 64 + ch * 8);
      }
#pragma unroll
      for (int mi = 0; mi < 4; mi++)
#pragma unroll
        for (int ni = 0; ni < 4; ni++)
          acc[mi][ni] = mfma16(af[mi], bfv[ni], acc[mi][ni]);
    }
  }

  const float qscale = (p0 < 1024) ? 0.125f * LOG2E : 1.0f;  // block-uniform
#pragma unroll
  for (int mi = 0; mi < 4; mi++) {
#pragma unroll
    for (int ni = 0; ni < 4; ni++) {
      int pb = p0 + wm * 64 + mi * 16 + quad * 4;  // channel base (mult of 4)
      int s  = s0 + wn * 64 + ni * 16 + l15;       // token
      int b = s >> 11, s2 = s & 2047;
      if (p0 < 2048) {  // q/k: uniform per block
        int part = pb >> 10, h = (pb & 1023) >> 6, dhb = pb & 63;
        bf16x4 o = {(__bf16)((acc[mi][ni][0] + bias[pb]) * qscale),
                    (__bf16)((acc[mi][ni][1] + bias[pb + 1]) * qscale),
                    (__bf16)((acc[mi][ni][2] + bias[pb + 2]) * qscale),
                    (__bf16)((acc[mi][ni][3] + bias[pb + 3]) * qscale)};
        *(bf16x4*)(qk + (size_t)part * 4194304 +
                   ((size_t)((b * 16 + h) * 2048 + s2)) * 64 + dhb) = o;
      } else {  // v -> v^T with per-chunk key permutation
        int h = (pb & 1023) >> 6, dhb = pb & 63;
        int off = s2 & 63, t = off >> 4, qd = (off >> 2) & 3, rr = off & 3;
        int ps2 = (s2 & ~63) | ((t >> 1) * 32 + qd * 8 + (t & 1) * 4 + rr);
#pragma unroll
        for (int r = 0; r < 4; r++)
          vtb[((size_t)((b * 16 + h) * 64 + dhb + r)) * 2048 + ps2] =
              (__bf16)(acc[mi][ni][r] + bias[pb + r]);
      }
    }
  }
}

// ---------------------------------------------------------------------------
// Output projection, 64x128 tile: grid (8, 64) = 512 blocks.  fp32 out + bias.
// ---------------------------------------------------------------------------
__global__ __launch_bounds__(256)
void gemm_proj(const __bf16* __restrict__ A, const __bf16* __restrict__ BT,
               const float* __restrict__ bias, float* __restrict__ Cout, int N) {
  const int K = 1024;
  __shared__ alignas(16) __bf16 As[64 * 64];
  __shared__ alignas(16) __bf16 Bs[128 * 64];
  const int tid = threadIdx.x;
  const int wave = tid >> 6, lane = tid & 63;
  const int wm = wave >> 1, wn = wave & 1;
  const int quad = lane >> 4, l15 = lane & 15;
  const int m0 = blockIdx.y * 64, n0 = blockIdx.x * 128;
  const int srow8 = lane >> 3, sc8 = lane & 7;
  const int sswz = sc8 ^ srow8;

  floatx4 acc[2][4] = {};

  for (int kb = 0; kb < K; kb += 64) {
    __syncthreads();
#pragma unroll
    for (int t = 0; t < 2; t++) {
      int rbase = (wave * 2 + t) * 8;
      load_lds16(A + (size_t)(m0 + rbase + srow8) * K + kb + sswz * 8,
                 As + rbase * 64);
    }
#pragma unroll
    for (int t = 0; t < 4; t++) {
      int rbase = (wave * 4 + t) * 8;
      load_lds16(BT + (size_t)(n0 + rbase + srow8) * K + kb + sswz * 8,
                 Bs + rbase * 64);
    }
    __syncthreads();
#pragma unroll
    for (int ks = 0; ks < 2; ks++) {
      bf16x8 af[2], bfv[4];
      int ch = (ks * 4 + quad) ^ (l15 & 7);
#pragma unroll
      for (int t = 0; t < 2; t++)
        af[t] = *(const bf16x8*)(As + (wm * 32 + t * 16 + l15) * 64 + ch * 8);
#pragma unroll
      for (int t = 0; t < 4; t++)
        bfv[t] = *(const bf16x8*)(Bs + (wn * 64 + t * 16 + l15) * 64 + ch * 8);
#pragma unroll
      for (int mi = 0; mi < 2; mi++)
#pragma unroll
        for (int ni = 0; ni < 4; ni++)
          acc[mi][ni] = mfma16(af[mi], bfv[ni], acc[mi][ni]);
    }
  }

#pragma unroll
  for (int mi = 0; mi < 2; mi++)
#pragma unroll
    for (int ni = 0; ni < 4; ni++) {
      int n = n0 + wn * 64 + ni * 16 + l15;
#pragma unroll
      for (int r = 0; r < 4; r++) {
        int m = m0 + wm * 32 + mi * 16 + quad * 4 + r;
        Cout[(size_t)m * N + n] = acc[mi][ni][r] + bias[n];
      }
    }
}

// ---------------------------------------------------------------------------
// Causal flash attention v15: 8-wave blocks, 2-way key split, lean softmax.
// v14 post-mortem: uniform pairing halved resident waves (8/CU const) and
// regressed; occupancy is the lever, serial per-chunk latency the limiter.
// v15, on the v13 chassis (1024 blocks = strip x bh, longest-first):
//  - Block = 8 waves (512 thr).  half = wave>>2 picks keys 0-31 / 32-63 of
//    each chunk; qw = wave&3 picks the 16-q tile.  Per-wave per-chunk work
//    halves (4 QK + 8 PV MFMA, 8 exp2); one pairwise (m,l,O) LDS merge at
//    the end.  Per-wave state shrinks (st[2], pB[2]) -> VGPR target <=64
//    so 4 blocks/CU = 32 waves/CU (LDS 4x32KB=128KB) become possible.
//  - Softmax de-serialized: lrun kept as per-quad PARTIAL (cross-quad sum
//    tree -> one post-loop reduction, -2 serial shfl/chunk); p = exp2(st -
//    mrun_old) computed UNCONDITIONALLY in parallel with the max tree
//    (defer-max: mrun rarely moves; rare rescale multiplies p/ssum/oacc by
//    exp2(m_old-m_new), exact).  mrun init 0.0 keeps the fixup finite.
//  - K/V staged in LDS via global_load_lds (XOR swizzle), double-buffered;
//    per chunk each wave issues 1 K + 1 V DMA; counted vmcnt(3) leaves
//    [am_nxt + 2 next-chunk DMAs] in flight.
// ---------------------------------------------------------------------------
__global__ __launch_bounds__(512)
void flash_attn(const __bf16* __restrict__ q, const __bf16* __restrict__ k,
                const __bf16* __restrict__ vt, const int* __restrict__ amask,
                __bf16* __restrict__ ctx) {
  const int S = 2048;
  __shared__ alignas(16) __bf16 smem[4][4096];  // K0,K1,V0,V1 (8KB each)
  const int bid = blockIdx.x;
  const int jb = 31 - (bid >> 5);    // strip, longest first
  const int bh = bid & 31;           // bh%8 = XCD -> per-head K/V L2 locality
  const int b = bh >> 4, h = bh & 15;
  const int wave = threadIdx.x >> 6, lane = threadIdx.x & 63;
  const int half = wave >> 2, qw = wave & 3;
  const int quad = lane >> 4, l15 = lane & 15;
  const int srow8 = lane >> 3, sc8 = lane & 7;
  const int sswz = sc8 ^ srow8;
  const int Q0 = jb * 64;
  const int qrow = Q0 + qw * 16 + l15;  // this wave's query rows

  const __bf16* qp  = q  + (size_t)bh * S * 64;
  const __bf16* kp0 = k  + (size_t)bh * S * 64;
  const __bf16* vp0 = vt + (size_t)bh * 64 * S;

  // Q fragments (issued first -> oldest in vm queue, drained by 1st vmcnt)
  bf16x8 qf[2];
#pragma unroll
  for (int ks = 0; ks < 2; ks++)
    qf[ks] = *(const bf16x8*)(qp + (size_t)qrow * 64 + ks * 32 + quad * 8);

  // amask for chunk 0 BEFORE the DMAs -> ages ahead of the stage ops
  int am_cur = amask[b * S + lane];
  int am_nxt = 0;

  // stage chunk cc into buffer bb: each of 8 waves stages 8 rows of K and V
  // (1 DMA each).  K rows = keys (contiguous); V rows = dh (stride S).
  // XOR pre-swizzled global source, linear LDS dest.
  auto STAGE = [&](int bb, int cc) {
    const int rbase = wave * 8;
    load_lds16(kp0 + (size_t)cc * 4096 + (size_t)(rbase + srow8) * 64 +
                   sswz * 8,
               &smem[bb][rbase * 64]);
    load_lds16(vp0 + (size_t)(rbase + srow8) * S + cc * 64 + sswz * 8,
               &smem[2 + bb][rbase * 64]);
  };

  STAGE(0, 0);

  float mrun = 0.0f, lrun = 0.0f;  // lrun = per-quad PARTIAL sum
  floatx4 oacc[4] = {};  // [dh-tile]; col(l15)=q, row(quad*4+r)=dh

  for (int c = 0; c <= jb; c++) {
    const int cur = c & 1;
    if (c < jb) {
      am_nxt = amask[b * S + (c + 1) * 64 + lane];  // before DMAs: older
      STAGE(cur ^ 1, c + 1);
      // leave [am_nxt + stage(c+1) x2] = 3 in flight; drain stage(c)
      asm volatile("s_waitcnt vmcnt(3)" ::: "memory");
    } else {
      asm volatile("s_waitcnt vmcnt(0)" ::: "memory");
    }
    __builtin_amdgcn_s_barrier();          // chunk c data visible to all
    __builtin_amdgcn_sched_barrier(0);     // no ds_read hoist above barrier

    // S^T = K.Q^T on this wave's 32-key half: col(l15)=q, row(quad*4+r)=key
    floatx4 st[2] = {};
    __builtin_amdgcn_s_setprio(1);
#pragma unroll
    for (int ks = 0; ks < 2; ks++) {
      const int ch = (ks * 4 + quad) ^ (l15 & 7);
      bf16x8 kf[2];
#pragma unroll
      for (int nt = 0; nt < 2; nt++)
        kf[nt] = *(const bf16x8*)(&smem[cur][((half * 2 + nt) * 16 + l15) * 64 +
                                            ch * 8]);
#pragma unroll
      for (int nt = 0; nt < 2; nt++)
        st[nt] = mfma16(kf[nt], qf[ks], st[nt]);
    }
    __builtin_amdgcn_s_setprio(0);

    unsigned long long pm = __ballot(am_cur == 0);
    if (pm == 0) {  // no padding (wave-uniform; true for all-ones mask)
      if (c == jb) {  // diagonal chunk: local causal mask
#pragma unroll
        for (int nt = 0; nt < 2; nt++) {
          int kl = (half * 2 + nt) * 16 + quad * 4;
#pragma unroll
          for (int r = 0; r < 4; r++) {
            bool masked = kl + r > qw * 16 + l15;
            st[nt][r] = masked ? MASKVAL : st[nt][r];
          }
        }
      }
    } else {
#pragma unroll
      for (int nt = 0; nt < 2; nt++) {
        int kl = (half * 2 + nt) * 16 + quad * 4;
#pragma unroll
        for (int r = 0; r < 4; r++) {
          bool pad = (pm >> (kl + r)) & 1ull;
          bool masked = pad || ((c == jb) && (kl + r > qw * 16 + l15));
          st[nt][r] = masked ? MASKVAL : st[nt][r];
        }
      }
    }

    // lean online softmax (log2 domain, per q = l15):
    // p computed unconditionally vs mrun_old, in parallel with the max tree;
    // defer-max (T13, THR=8) makes the rescale branch rare.
    floatx4 pex[2];
#pragma unroll
    for (int nt = 0; nt < 2; nt++)
#pragma unroll
      for (int r = 0; r < 4; r++)
        pex[nt][r] = exp2f(st[nt][r] - mrun);
    float ssum = ((pex[0][0] + pex[0][1]) + (pex[0][2] + pex[0][3])) +
                 ((pex[1][0] + pex[1][1]) + (pex[1][2] + pex[1][3]));
    float rm = fmaxf(fmaxf(fmaxf(st[0][0], st[0][1]),
                           fmaxf(st[0][2], st[0][3])),
                     fmaxf(fmaxf(st[1][0], st[1][1]),
                           fmaxf(st[1][2], st[1][3])));
    rm = fmaxf(rm, __shfl_xor(rm, 16, 64));
    rm = fmaxf(rm, __shfl_xor(rm, 32, 64));
    if (!__all(rm - mrun <= 8.0f)) {  // rare, wave-uniform
      float mnew = fmaxf(mrun, rm);
      float al = exp2f(mrun - mnew);
      mrun = mnew;
      lrun *= al;
      ssum *= al;
#pragma unroll
      for (int nt = 0; nt < 2; nt++)
#pragma unroll
        for (int r = 0; r < 4; r++) pex[nt][r] *= al;
#pragma unroll
      for (int nd = 0; nd < 4; nd++)
#pragma unroll
        for (int r = 0; r < 4; r++) oacc[nd][r] *= al;
    }
    lrun += ssum;

    // pack P tiles (B-operand == C-layout)
    bf16x4 pB0 = {(__bf16)pex[0][0], (__bf16)pex[0][1],
                  (__bf16)pex[0][2], (__bf16)pex[0][3]};
    bf16x4 pB1 = {(__bf16)pex[1][0], (__bf16)pex[1][1],
                  (__bf16)pex[1][2], (__bf16)pex[1][3]};

    // O^T += V^T P^T on this half's 32 keys; one 16B V frag feeds both
    // key-subtiles (half*2, half*2+1)
    __builtin_amdgcn_s_setprio(1);
    {
      const int chv = (half * 4 + quad) ^ (l15 & 7);
#pragma unroll
      for (int nd = 0; nd < 4; nd++) {
        bf16x8 v8 =
            *(const bf16x8*)(&smem[2 + cur][(nd * 16 + l15) * 64 + chv * 8]);
        bf16x4 vA0 = {v8[0], v8[1], v8[2], v8[3]};
        bf16x4 vA1 = {v8[4], v8[5], v8[6], v8[7]};
        oacc[nd] = mfma_pv(vA0, pB0, oacc[nd]);
        oacc[nd] = mfma_pv(vA1, pB1, oacc[nd]);
      }
    }
    __builtin_amdgcn_s_setprio(0);

    am_cur = am_nxt;
    __builtin_amdgcn_s_barrier();  // all waves done reading buf cur
  }

  // deferred cross-quad l reduction (once per strip instead of per chunk)
  lrun += __shfl_xor(lrun, 16, 64);
  lrun += __shfl_xor(lrun, 32, 64);

  // ---- pairwise key-half merge: waves 4-7 publish, waves 0-3 combine ----
  float* mb = (float*)smem;  // 8192 floats available; need 4*18*64 = 4608
  if (half == 1) {
#pragma unroll
    for (int nd = 0; nd < 4; nd++)
#pragma unroll
      for (int r = 0; r < 4; r++)
        mb[(qw * 18 + nd * 4 + r) * 64 + lane] = oacc[nd][r];
    mb[(qw * 18 + 16) * 64 + lane] = mrun;
    mb[(qw * 18 + 17) * 64 + lane] = lrun;
  }
  __syncthreads();
  if (half == 1) return;

  const float m1 = mb[(qw * 18 + 16) * 64 + lane];
  const float l1 = mb[(qw * 18 + 17) * 64 + lane];
  const float ms = fmaxf(mrun, m1);
  const float f0 = exp2f(mrun - ms), f1 = exp2f(m1 - ms);
  const float linv = 1.0f / (f0 * lrun + f1 * l1);
#pragma unroll
  for (int nd = 0; nd < 4; nd++) {
    float ov[4];
#pragma unroll
    for (int r = 0; r < 4; r++)
      ov[r] = (f0 * oacc[nd][r] + f1 * mb[(qw * 18 + nd * 4 + r) * 64 + lane]) *
              linv;
    bf16x4 o = {(__bf16)ov[0], (__bf16)ov[1], (__bf16)ov[2], (__bf16)ov[3]};
    *(bf16x4*)(ctx + ((size_t)(b * 2048 + qrow)) * 1024 + h * 64 + nd * 16 +
               quad * 4) = o;
  }
}

// ---------------------------------------------------------------------------
extern "C" void kernel_launch(void* const* d_in, const int* in_sizes, int n_in,
                              void* d_out, int out_size, void* d_ws, size_t ws_size,
                              hipStream_t stream) {
  const float* x  = (const float*)d_in[0];
  const int*   am = (const int*)d_in[1];
  const float* Wq = (const float*)d_in[2];
  const float* bq = (const float*)d_in[3];
  const float* Aq = (const float*)d_in[4];
  const float* Bq = (const float*)d_in[5];
  const float* Wp = (const float*)d_in[6];
  const float* bp = (const float*)d_in[7];
  const float* Ap = (const float*)d_in[8];
  const float* Bp = (const float*)d_in[9];

  __bf16* wqkvT = (__bf16*)d_ws;                       // [3072][1024]
  __bf16* wpT   = wqkvT + (size_t)3072 * 1024;         // [1024][1024]
  __bf16* xbf   = wpT   + (size_t)1024 * 1024;         // [4096][1024]
  __bf16* qbuf  = xbf   + (size_t)4096 * 1024;         // [2][16][2048][64] (+kbuf)
  __bf16* vtbuf = qbuf  + (size_t)2 * 4194304;         // [2][16][64][2048] permuted
  __bf16* ctxb  = vtbuf + (size_t)4194304;             // [4096][1024]

  fold_wt2<<<dim3(64, 16), 256, 0, stream>>>(Wq, Aq, Bq, wqkvT,
                                             Wp, Ap, Bp, wpT);
  cast_x<<<4096, 256, 0, stream>>>(x, xbf);

  gemm_qkv<<<dim3(32, 24), 256, 0, stream>>>(wqkvT, xbf, bq, qbuf, vtbuf);
  flash_attn<<<1024, 512, 0, stream>>>(qbuf, qbuf + 4194304, vtbuf, am, ctxb);
  gemm_proj<<<dim3(8, 64), 256, 0, stream>>>(ctxb, wpT, bp, (float*)d_out, 1024);
}

// Round 5
// 210.328 us; speedup vs baseline: 1.0025x; 1.0025x over previous
//
#include <hip/hip_runtime.h>
#include <hip/hip_bf16.h>

#define LOG2E 1.4426950408889634f
// reference: mask(-1e9) BEFORE scale(/8); log2e folded into Q pre-scale
#define MASKVAL (-1.25e8f * LOG2E)

typedef __bf16 bf16x8 __attribute__((ext_vector_type(8)));
typedef __bf16 bf16x4 __attribute__((ext_vector_type(4)));
typedef short  shortx4 __attribute__((ext_vector_type(4)));
typedef float  floatx4 __attribute__((ext_vector_type(4)));

__device__ __forceinline__ floatx4 mfma16(bf16x8 a, bf16x8 b, floatx4 c) {
  return __builtin_amdgcn_mfma_f32_16x16x32_bf16(a, b, c, 0, 0, 0);
}

// 16x16x16 bf16 MFMA: B-operand layout (n=l15, k=quad*4+i) == S^T C-tile
// layout -> P feeds PV with zero cross-lane transforms.
__device__ __forceinline__ floatx4 mfma_pv(bf16x4 a, bf16x4 b, floatx4 c) {
#if __has_builtin(__builtin_amdgcn_mfma_f32_16x16x16_bf16)
  return __builtin_amdgcn_mfma_f32_16x16x16_bf16(a, b, c, 0, 0, 0);
#else
  shortx4 as, bs;
  __builtin_memcpy(&as, &a, 8);
  __builtin_memcpy(&bs, &b, 8);
  return __builtin_amdgcn_mfma_f32_16x16x16bf16_1k(as, bs, c, 0, 0, 0);
#endif
}

// async global->LDS, 16B per lane. Dest = wave-uniform base + lane*16.
__device__ __forceinline__ void load_lds16(const __bf16* g, __bf16* l) {
  __builtin_amdgcn_global_load_lds(
      (const __attribute__((address_space(1))) void*)g,
      (__attribute__((address_space(3))) void*)l, 16, 0, 0);
}

// ---------------------------------------------------------------------------
// Fold LoRA into weights, emit W_eff^T bf16 [ncols][1024].  Both weight sets
// in one launch: blockIdx.x < 48 -> qkv (ncols 3072), else proj (ncols 1024).
// ---------------------------------------------------------------------------
__global__ __launch_bounds__(256)
void fold_wt2(const float* __restrict__ Wq, const float* __restrict__ Aq,
              const float* __restrict__ Bq, __bf16* __restrict__ WTq,
              const float* __restrict__ Wp, const float* __restrict__ Ap,
              const float* __restrict__ Bp, __bf16* __restrict__ WTp) {
  __shared__ float tile[64][65];
  __shared__ float sLb[8][64];
  const int bx = blockIdx.x;
  const bool isQ = bx < 48;
  const float* W  = isQ ? Wq : Wp;
  const float* La = isQ ? Aq : Ap;
  const float* Lb = isQ ? Bq : Bp;
  __bf16* WT = isQ ? WTq : WTp;
  const int ncols = isQ ? 3072 : 1024;
  const int nt = (isQ ? bx : bx - 48) * 64;
  const int kt = blockIdx.y * 64;
  const int tid = threadIdx.x;
  const int tx = tid & 63, ty = tid >> 6;

  float rLa[8];
  *(float4*)&rLa[0] = *(const float4*)(La + (size_t)(kt + tx) * 8);
  *(float4*)&rLa[4] = *(const float4*)(La + (size_t)(kt + tx) * 8 + 4);

#pragma unroll
  for (int rep = 0; rep < 2; rep++) {
    int idx = tid + rep * 256;
    sLb[idx >> 6][idx & 63] = Lb[(size_t)(idx >> 6) * ncols + nt + (idx & 63)];
  }
#pragma unroll
  for (int rep = 0; rep < 16; rep++) {
    int i = rep * 4 + ty;
    tile[i][tx] = W[(size_t)(kt + i) * ncols + nt + tx];
  }
  __syncthreads();
#pragma unroll
  for (int rep = 0; rep < 16; rep++) {
    int i = rep * 4 + ty;
    int n = nt + i, k = kt + tx;
    float acc = tile[tx][i];
#pragma unroll
    for (int r = 0; r < 8; r++)
      acc += 2.0f * rLa[r] * sLb[r][i];  // LORA_SCALING = 2
    WT[(size_t)n * 1024 + k] = (__bf16)acc;
  }
}

__global__ __launch_bounds__(256)
void cast_x(const float* __restrict__ x, __bf16* __restrict__ o) {
  int i = blockIdx.x * 256 + threadIdx.x;
  float4 v = ((const float4*)x)[i];
  bf16x4 r = {(__bf16)v.x, (__bf16)v.y, (__bf16)v.z, (__bf16)v.w};
  ((bf16x4*)o)[i] = r;
}

// ---------------------------------------------------------------------------
// Fused QKV projection, swapped orientation: D[p][s] = sum_k WT[p][k] X[s][k].
// 128x128 tiles, BK=64, global_load_lds staging, XOR-swizzled LDS.
// Q channels (p<1024) pre-scaled by 0.125*LOG2E.
// V is written to vtb with keys PERMUTED within each 64-key chunk so the
// flash PV A-fragments are 16B-contiguous: key off (t=off>>4, qd=(off>>2)&3,
// r=off&3) stored at position (t>>1)*32 + qd*8 + (t&1)*4 + r.
// ---------------------------------------------------------------------------
__global__ __launch_bounds__(256)
void gemm_qkv(const __bf16* __restrict__ WT, const __bf16* __restrict__ X,
              const float* __restrict__ bias, __bf16* __restrict__ qk,
              __bf16* __restrict__ vtb) {
  const int K = 1024;
  __shared__ alignas(16) __bf16 As[128 * 64];
  __shared__ alignas(16) __bf16 Bs[128 * 64];
  const int tid = threadIdx.x;
  const int wave = tid >> 6, lane = tid & 63;
  const int wm = wave >> 1, wn = wave & 1;
  const int quad = lane >> 4, l15 = lane & 15;
  const int p0 = blockIdx.y * 128, s0 = blockIdx.x * 128;
  const int srow8 = lane >> 3, sc8 = lane & 7;
  const int sswz = sc8 ^ srow8;

  floatx4 acc[4][4] = {};

  for (int kb = 0; kb < K; kb += 64) {
    __syncthreads();
#pragma unroll
    for (int t = 0; t < 4; t++) {
      int rbase = (wave * 4 + t) * 8;
      int row = rbase + srow8;
      load_lds16(WT + (size_t)(p0 + row) * K + kb + sswz * 8, As + rbase * 64);
      load_lds16(X + (size_t)(s0 + row) * K + kb + sswz * 8, Bs + rbase * 64);
    }
    __syncthreads();
#pragma unroll
    for (int ks = 0; ks < 2; ks++) {
      bf16x8 af[4], bfv[4];
#pragma unroll
      for (int t = 0; t < 4; t++) {
        int ra = wm * 64 + t * 16 + l15;
        int rb = wn * 64 + t * 16 + l15;
        int ch = (ks * 4 + quad) ^ (l15 & 7);
        af[t]  = *(const bf16x8*)(As + ra * 64 + ch * 8);
        bfv[t] = *(const bf16x8*)(Bs + rb * 64 + ch * 8);
      }
#pragma unroll
      for (int mi = 0; mi < 4; mi++)
#pragma unroll
        for (int ni = 0; ni < 4; ni++)
          acc[mi][ni] = mfma16(af[mi], bfv[ni], acc[mi][ni]);
    }
  }

  const float qscale = (p0 < 1024) ? 0.125f * LOG2E : 1.0f;  // block-uniform
#pragma unroll
  for (int mi = 0; mi < 4; mi++) {
#pragma unroll
    for (int ni = 0; ni < 4; ni++) {
      int pb = p0 + wm * 64 + mi * 16 + quad * 4;  // channel base (mult of 4)
      int s  = s0 + wn * 64 + ni * 16 + l15;       // token
      int b = s >> 11, s2 = s & 2047;
      if (p0 < 2048) {  // q/k: uniform per block
        int part = pb >> 10, h = (pb & 1023) >> 6, dhb = pb & 63;
        bf16x4 o = {(__bf16)((acc[mi][ni][0] + bias[pb]) * qscale),
                    (__bf16)((acc[mi][ni][1] + bias[pb + 1]) * qscale),
                    (__bf16)((acc[mi][ni][2] + bias[pb + 2]) * qscale),
                    (__bf16)((acc[mi][ni][3] + bias[pb + 3]) * qscale)};
        *(bf16x4*)(qk + (size_t)part * 4194304 +
                   ((size_t)((b * 16 + h) * 2048 + s2)) * 64 + dhb) = o;
      } else {  // v -> v^T with per-chunk key permutation
        int h = (pb & 1023) >> 6, dhb = pb & 63;
        int off = s2 & 63, t = off >> 4, qd = (off >> 2) & 3, rr = off & 3;
        int ps2 = (s2 & ~63) | ((t >> 1) * 32 + qd * 8 + (t & 1) * 4 + rr);
#pragma unroll
        for (int r = 0; r < 4; r++)
          vtb[((size_t)((b * 16 + h) * 64 + dhb + r)) * 2048 + ps2] =
              (__bf16)(acc[mi][ni][r] + bias[pb + r]);
      }
    }
  }
}

// ---------------------------------------------------------------------------
// Output projection, 64x128 tile: grid (8, 64) = 512 blocks.  fp32 out + bias.
// ---------------------------------------------------------------------------
__global__ __launch_bounds__(256)
void gemm_proj(const __bf16* __restrict__ A, const __bf16* __restrict__ BT,
               const float* __restrict__ bias, float* __restrict__ Cout, int N) {
  const int K = 1024;
  __shared__ alignas(16) __bf16 As[64 * 64];
  __shared__ alignas(16) __bf16 Bs[128 * 64];
  const int tid = threadIdx.x;
  const int wave = tid >> 6, lane = tid & 63;
  const int wm = wave >> 1, wn = wave & 1;
  const int quad = lane >> 4, l15 = lane & 15;
  const int m0 = blockIdx.y * 64, n0 = blockIdx.x * 128;
  const int srow8 = lane >> 3, sc8 = lane & 7;
  const int sswz = sc8 ^ srow8;

  floatx4 acc[2][4] = {};

  for (int kb = 0; kb < K; kb += 64) {
    __syncthreads();
#pragma unroll
    for (int t = 0; t < 2; t++) {
      int rbase = (wave * 2 + t) * 8;
      load_lds16(A + (size_t)(m0 + rbase + srow8) * K + kb + sswz * 8,
                 As + rbase * 64);
    }
#pragma unroll
    for (int t = 0; t < 4; t++) {
      int rbase = (wave * 4 + t) * 8;
      load_lds16(BT + (size_t)(n0 + rbase + srow8) * K + kb + sswz * 8,
                 Bs + rbase * 64);
    }
    __syncthreads();
#pragma unroll
    for (int ks = 0; ks < 2; ks++) {
      bf16x8 af[2], bfv[4];
      int ch = (ks * 4 + quad) ^ (l15 & 7);
#pragma unroll
      for (int t = 0; t < 2; t++)
        af[t] = *(const bf16x8*)(As + (wm * 32 + t * 16 + l15) * 64 + ch * 8);
#pragma unroll
      for (int t = 0; t < 4; t++)
        bfv[t] = *(const bf16x8*)(Bs + (wn * 64 + t * 16 + l15) * 64 + ch * 8);
#pragma unroll
      for (int mi = 0; mi < 2; mi++)
#pragma unroll
        for (int ni = 0; ni < 4; ni++)
          acc[mi][ni] = mfma16(af[mi], bfv[ni], acc[mi][ni]);
    }
  }

#pragma unroll
  for (int mi = 0; mi < 2; mi++)
#pragma unroll
    for (int ni = 0; ni < 4; ni++) {
      int n = n0 + wn * 64 + ni * 16 + l15;
#pragma unroll
      for (int r = 0; r < 4; r++) {
        int m = m0 + wm * 32 + mi * 16 + quad * 4 + r;
        Cout[(size_t)m * N + n] = acc[mi][ni][r] + bias[n];
      }
    }
}

// ---------------------------------------------------------------------------
// Causal flash attention v16: v13 chassis + serial-chain surgery.
// v15 post-mortem: +occupancy did NOT help -> the limiter is the per-chunk
// serial dependency chain (~3800 cyc/chunk measured), not wave supply.
// v16 shortens the chain, on the best-measured v13 structure (1024 blocks x
// 4 waves, 16q/wave, 64-key LDS chunks, XOR swizzle):
//  1. CROSS-CHUNK PIPELINING: K staged 2 chunks ahead (still 2 K buffers:
//     K(i) is dead at iter i because QK(i) ran at iter i-1).  QK(i+1) is
//     computed INSIDE body i, overlapping softmax(i)+PV(i) -> chain becomes
//     max(QK, softmax+PV) instead of their sum.  Scores ping-pong between
//     named stA/stB (rule #20: no runtime-indexed register arrays).
//  2. ONE barrier per iter (was 2).  Proof: stage at body i writes Ks[i&1]
//     (last read: QK(i) at body i-1) and Vs[(i+1)&1] (last read: PV(i-1) at
//     body i-1); both reads complete before body i's top barrier.  DMA
//     visibility: each wave drains its own DMAs (vmcnt(0)) then barriers ->
//     all waves' staged data visible after the barrier.
//  3. Shuffle-free fast-path softmax: defer check on IN-LANE max only
//     (in-lane max <= mrun+8 for all lanes => cross-quad max too); the two
//     serial cross-lane shfls run only on the rare rescale path.  lrun is a
//     per-quad partial, cross-quad-summed once in the epilogue (v15).
//     Padding ballot hoisted to a one-time pre-scan (mask all-ones here).
// ---------------------------------------------------------------------------
__global__ __launch_bounds__(256)
void flash_attn(const __bf16* __restrict__ q, const __bf16* __restrict__ k,
                const __bf16* __restrict__ vt, const int* __restrict__ amask,
                __bf16* __restrict__ ctx) {
  const int S = 2048;
  __shared__ alignas(16) __bf16 Ks[2][64 * 64];
  __shared__ alignas(16) __bf16 Vs[2][64 * 64];
  const int bid = blockIdx.x;
  const int jb = 31 - (bid >> 5);    // strip, longest first
  const int bh = bid & 31;           // bh%8 = XCD -> per-head K/V L2 locality
  const int b = bh >> 4, h = bh & 15;
  const int wave = threadIdx.x >> 6, lane = threadIdx.x & 63;
  const int quad = lane >> 4, l15 = lane & 15;
  const int srow8 = lane >> 3, sc8 = lane & 7;
  const int sswz = sc8 ^ srow8;
  const int Q0 = jb * 64;
  const int qrow = Q0 + wave * 16 + l15;  // this wave's query rows

  const __bf16* qp  = q  + (size_t)bh * S * 64;
  const __bf16* kp0 = k  + (size_t)bh * S * 64;
  const __bf16* vp0 = vt + (size_t)bh * 64 * S;

  auto STAGE_K = [&](int bb, int cc) {
#pragma unroll
    for (int t = 0; t < 2; t++) {
      int rbase = (wave * 2 + t) * 8;
      load_lds16(kp0 + (size_t)cc * 4096 + (size_t)(rbase + srow8) * 64 +
                     sswz * 8,
                 &Ks[bb][rbase * 64]);
    }
  };
  auto STAGE_V = [&](int bb, int cc) {
#pragma unroll
    for (int t = 0; t < 2; t++) {
      int rbase = (wave * 2 + t) * 8;
      load_lds16(vp0 + (size_t)(rbase + srow8) * S + cc * 64 + sswz * 8,
                 &Vs[bb][rbase * 64]);
    }
  };

  // Q fragments
  bf16x8 qf[2];
#pragma unroll
  for (int ks = 0; ks < 2; ks++)
    qf[ks] = *(const bf16x8*)(qp + (size_t)qrow * 64 + ks * 32 + quad * 8);

  // one-time padding pre-scan over this strip's key range
  int anyp = 0;
  for (int c = 0; c <= jb; c++)
    anyp |= (amask[b * S + c * 64 + lane] == 0) ? 1 : 0;
  const bool padded = (__ballot(anyp) != 0ull);  // wave-uniform

  // prologue staging: K(0), V(0), and K(1) (for the in-body QK(1))
  STAGE_K(0, 0);
  STAGE_V(0, 0);
  if (jb >= 1) STAGE_K(1, 1);
  asm volatile("s_waitcnt vmcnt(0)" ::: "memory");
  __builtin_amdgcn_s_barrier();
  __builtin_amdgcn_sched_barrier(0);

  float mrun = 0.0f, lrun = 0.0f;  // lrun = per-quad PARTIAL sum
  floatx4 oacc[4] = {};  // [dh-tile]; col(l15)=q, row(quad*4+r)=dh
  floatx4 stA[4], stB[4];

  // QK(0) -> stA
  {
#pragma unroll
    for (int nt = 0; nt < 4; nt++) stA[nt] = floatx4{0.f, 0.f, 0.f, 0.f};
#pragma unroll
    for (int ks = 0; ks < 2; ks++) {
      const int ch = (ks * 4 + quad) ^ (l15 & 7);
      bf16x8 kf[4];
#pragma unroll
      for (int nt = 0; nt < 4; nt++)
        kf[nt] = *(const bf16x8*)(&Ks[0][(nt * 16 + l15) * 64 + ch * 8]);
#pragma unroll
      for (int nt = 0; nt < 4; nt++)
        stA[nt] = mfma16(kf[nt], qf[ks], stA[nt]);
    }
  }

  // body i: mask/softmax/PV on CUR (= scores i), compute NXT = QK(i+1).
  auto BODY = [&](int i, floatx4 (&CUR)[4], floatx4 (&NXT)[4]) {
    asm volatile("s_waitcnt vmcnt(0)" ::: "memory");
    __builtin_amdgcn_s_barrier();
    __builtin_amdgcn_sched_barrier(0);
    if (i < jb) {
      STAGE_V((i + 1) & 1, i + 1);          // V(i+1)
      if (i + 1 < jb) STAGE_K(i & 1, i + 2);  // K(i+2) into buffer K(i) freed
    }

    // masking
    if (padded) {
      int am_c = amask[b * S + i * 64 + lane];  // rare path, latency exposed
      unsigned long long pm = __ballot(am_c == 0);
#pragma unroll
      for (int nt = 0; nt < 4; nt++) {
        int kl = nt * 16 + quad * 4;
#pragma unroll
        for (int r = 0; r < 4; r++) {
          bool pad = (pm >> (kl + r)) & 1ull;
          bool masked = pad || ((i == jb) && (kl + r > wave * 16 + l15));
          CUR[nt][r] = masked ? MASKVAL : CUR[nt][r];
        }
      }
    } else if (i == jb) {  // diagonal chunk: local causal mask only
#pragma unroll
      for (int nt = 0; nt < 4; nt++) {
        int kl = nt * 16 + quad * 4;
#pragma unroll
        for (int r = 0; r < 4; r++) {
          bool masked = kl + r > wave * 16 + l15;
          CUR[nt][r] = masked ? MASKVAL : CUR[nt][r];
        }
      }
    }

    // shuffle-free fast-path softmax (log2 domain, per q = l15)
    float inm = fmaxf(
        fmaxf(fmaxf(fmaxf(CUR[0][0], CUR[0][1]), fmaxf(CUR[0][2], CUR[0][3])),
              fmaxf(fmaxf(CUR[1][0], CUR[1][1]), fmaxf(CUR[1][2], CUR[1][3]))),
        fmaxf(fmaxf(fmaxf(CUR[2][0], CUR[2][1]), fmaxf(CUR[2][2], CUR[2][3])),
              fmaxf(fmaxf(CUR[3][0], CUR[3][1]),
                    fmaxf(CUR[3][2], CUR[3][3]))));
#pragma unroll
    for (int nt = 0; nt < 4; nt++)
#pragma unroll
      for (int r = 0; r < 4; r++)
        CUR[nt][r] = exp2f(CUR[nt][r] - mrun);  // p vs mrun_old, exact
    float ssum = (((CUR[0][0] + CUR[0][1]) + (CUR[0][2] + CUR[0][3])) +
                  ((CUR[1][0] + CUR[1][1]) + (CUR[1][2] + CUR[1][3]))) +
                 (((CUR[2][0] + CUR[2][1]) + (CUR[2][2] + CUR[2][3])) +
                  ((CUR[3][0] + CUR[3][1]) + (CUR[3][2] + CUR[3][3])));
    if (!__all(inm - mrun <= 8.0f)) {  // rare rescale (wave-uniform)
      float rm = fmaxf(inm, __shfl_xor(inm, 16, 64));
      rm = fmaxf(rm, __shfl_xor(rm, 32, 64));
      float mnew = fmaxf(mrun, rm);
      float al = exp2f(mrun - mnew);
      mrun = mnew;
      lrun *= al;
      ssum *= al;
#pragma unroll
      for (int nt = 0; nt < 4; nt++)
#pragma unroll
        for (int r = 0; r < 4; r++) CUR[nt][r] *= al;
#pragma unroll
      for (int nd = 0; nd < 4; nd++)
#pragma unroll
        for (int r = 0; r < 4; r++) oacc[nd][r] *= al;
    }
    lrun += ssum;

    // pack P tiles (B-operand == C-layout)
    bf16x4 pB[4];
#pragma unroll
    for (int nt = 0; nt < 4; nt++) {
      bf16x4 pk = {(__bf16)CUR[nt][0], (__bf16)CUR[nt][1],
                   (__bf16)CUR[nt][2], (__bf16)CUR[nt][3]};
      pB[nt] = pk;
    }

    __builtin_amdgcn_s_setprio(1);
    // PV(i): O^T += V^T P^T, reads Vs[i&1]
#pragma unroll
    for (int tp = 0; tp < 2; tp++) {
      const int chv = (tp * 4 + quad) ^ (l15 & 7);
#pragma unroll
      for (int nd = 0; nd < 4; nd++) {
        bf16x8 v8 =
            *(const bf16x8*)(&Vs[i & 1][(nd * 16 + l15) * 64 + chv * 8]);
        bf16x4 vA0 = {v8[0], v8[1], v8[2], v8[3]};
        bf16x4 vA1 = {v8[4], v8[5], v8[6], v8[7]};
        oacc[nd] = mfma_pv(vA0, pB[2 * tp], oacc[nd]);
        oacc[nd] = mfma_pv(vA1, pB[2 * tp + 1], oacc[nd]);
      }
    }
    // QK(i+1) -> NXT, reads Ks[(i+1)&1]; independent of softmax(i)/PV(i),
    // overlaps them in the scheduler.
    if (i < jb) {
#pragma unroll
      for (int nt = 0; nt < 4; nt++) NXT[nt] = floatx4{0.f, 0.f, 0.f, 0.f};
#pragma unroll
      for (int ks = 0; ks < 2; ks++) {
        const int ch = (ks * 4 + quad) ^ (l15 & 7);
        bf16x8 kf[4];
#pragma unroll
        for (int nt = 0; nt < 4; nt++)
          kf[nt] = *(const bf16x8*)(&Ks[(i + 1) & 1][(nt * 16 + l15) * 64 +
                                                     ch * 8]);
#pragma unroll
        for (int nt = 0; nt < 4; nt++)
          NXT[nt] = mfma16(kf[nt], qf[ks], NXT[nt]);
      }
    }
    __builtin_amdgcn_s_setprio(0);
  };

  // ping-pong loop, static register indexing (rule #20)
  int i = 0;
  while (true) {
    BODY(i, stA, stB);
    if (++i > jb) break;
    BODY(i, stB, stA);
    if (++i > jb) break;
  }

  // deferred cross-quad l reduction (once per strip instead of per chunk)
  lrun += __shfl_xor(lrun, 16, 64);
  lrun += __shfl_xor(lrun, 32, 64);

  // epilogue: direct normalize + store (no merge)
  const float linv = 1.0f / lrun;
#pragma unroll
  for (int nd = 0; nd < 4; nd++) {
    bf16x4 o = {(__bf16)(oacc[nd][0] * linv), (__bf16)(oacc[nd][1] * linv),
                (__bf16)(oacc[nd][2] * linv), (__bf16)(oacc[nd][3] * linv)};
    *(bf16x4*)(ctx + ((size_t)(b * 2048 + qrow)) * 1024 + h * 64 + nd * 16 +
               quad * 4) = o;
  }
}

// ---------------------------------------------------------------------------
extern "C" void kernel_launch(void* const* d_in, const int* in_sizes, int n_in,
                              void* d_out, int out_size, void* d_ws, size_t ws_size,
                              hipStream_t stream) {
  const float* x  = (const float*)d_in[0];
  const int*   am = (const int*)d_in[1];
  const float* Wq = (const float*)d_in[2];
  const float* bq = (const float*)d_in[3];
  const float* Aq = (const float*)d_in[4];
  const float* Bq = (const float*)d_in[5];
  const float* Wp = (const float*)d_in[6];
  const float* bp = (const float*)d_in[7];
  const float* Ap = (const float*)d_in[8];
  const float* Bp = (const float*)d_in[9];

  __bf16* wqkvT = (__bf16*)d_ws;                       // [3072][1024]
  __bf16* wpT   = wqkvT + (size_t)3072 * 1024;         // [1024][1024]
  __bf16* xbf   = wpT   + (size_t)1024 * 1024;         // [4096][1024]
  __bf16* qbuf  = xbf   + (size_t)4096 * 1024;         // [2][16][2048][64] (+kbuf)
  __bf16* vtbuf = qbuf  + (size_t)2 * 4194304;         // [2][16][64][2048] permuted
  __bf16* ctxb  = vtbuf + (size_t)4194304;             // [4096][1024]

  fold_wt2<<<dim3(64, 16), 256, 0, stream>>>(Wq, Aq, Bq, wqkvT,
                                             Wp, Ap, Bp, wpT);
  cast_x<<<4096, 256, 0, stream>>>(x, xbf);

  gemm_qkv<<<dim3(32, 24), 256, 0, stream>>>(wqkvT, xbf, bq, qbuf, vtbuf);
  flash_attn<<<1024, 256, 0, stream>>>(qbuf, qbuf + 4194304, vtbuf, am, ctxb);
  gemm_proj<<<dim3(8, 64), 256, 0, stream>>>(ctxb, wpT, bp, (float*)d_out, 1024);
}

// Round 6
// 203.829 us; speedup vs baseline: 1.0345x; 1.0319x over previous
//
#include <hip/hip_runtime.h>
#include <hip/hip_bf16.h>

#define LOG2E 1.4426950408889634f
// reference: mask(-1e9) BEFORE scale(/8); log2e folded into Q pre-scale
#define MASKVAL (-1.25e8f * LOG2E)

typedef __bf16 bf16x8 __attribute__((ext_vector_type(8)));
typedef __bf16 bf16x4 __attribute__((ext_vector_type(4)));
typedef short  shortx4 __attribute__((ext_vector_type(4)));
typedef float  floatx4 __attribute__((ext_vector_type(4)));

__device__ __forceinline__ floatx4 mfma16(bf16x8 a, bf16x8 b, floatx4 c) {
  return __builtin_amdgcn_mfma_f32_16x16x32_bf16(a, b, c, 0, 0, 0);
}

// 16x16x16 bf16 MFMA: B-operand layout (n=l15, k=quad*4+i) == S^T C-tile
// layout -> P feeds PV with zero cross-lane transforms.
__device__ __forceinline__ floatx4 mfma_pv(bf16x4 a, bf16x4 b, floatx4 c) {
#if __has_builtin(__builtin_amdgcn_mfma_f32_16x16x16_bf16)
  return __builtin_amdgcn_mfma_f32_16x16x16_bf16(a, b, c, 0, 0, 0);
#else
  shortx4 as, bs;
  __builtin_memcpy(&as, &a, 8);
  __builtin_memcpy(&bs, &b, 8);
  return __builtin_amdgcn_mfma_f32_16x16x16bf16_1k(as, bs, c, 0, 0, 0);
#endif
}

// async global->LDS, 16B per lane. Dest = wave-uniform base + lane*16.
__device__ __forceinline__ void load_lds16(const __bf16* g, __bf16* l) {
  __builtin_amdgcn_global_load_lds(
      (const __attribute__((address_space(1))) void*)g,
      (__attribute__((address_space(3))) void*)l, 16, 0, 0);
}

// encourage v_max3_f32 fusion
__device__ __forceinline__ float max3f(float a, float b, float c) {
  return fmaxf(a, fmaxf(b, c));
}

// ---------------------------------------------------------------------------
// Fold LoRA into weights, emit W_eff^T bf16 [ncols][1024].  Both weight sets
// in one launch: blockIdx.x < 48 -> qkv (ncols 3072), else proj (ncols 1024).
// ---------------------------------------------------------------------------
__global__ __launch_bounds__(256)
void fold_wt2(const float* __restrict__ Wq, const float* __restrict__ Aq,
              const float* __restrict__ Bq, __bf16* __restrict__ WTq,
              const float* __restrict__ Wp, const float* __restrict__ Ap,
              const float* __restrict__ Bp, __bf16* __restrict__ WTp) {
  __shared__ float tile[64][65];
  __shared__ float sLb[8][64];
  const int bx = blockIdx.x;
  const bool isQ = bx < 48;
  const float* W  = isQ ? Wq : Wp;
  const float* La = isQ ? Aq : Ap;
  const float* Lb = isQ ? Bq : Bp;
  __bf16* WT = isQ ? WTq : WTp;
  const int ncols = isQ ? 3072 : 1024;
  const int nt = (isQ ? bx : bx - 48) * 64;
  const int kt = blockIdx.y * 64;
  const int tid = threadIdx.x;
  const int tx = tid & 63, ty = tid >> 6;

  float rLa[8];
  *(float4*)&rLa[0] = *(const float4*)(La + (size_t)(kt + tx) * 8);
  *(float4*)&rLa[4] = *(const float4*)(La + (size_t)(kt + tx) * 8 + 4);

#pragma unroll
  for (int rep = 0; rep < 2; rep++) {
    int idx = tid + rep * 256;
    sLb[idx >> 6][idx & 63] = Lb[(size_t)(idx >> 6) * ncols + nt + (idx & 63)];
  }
#pragma unroll
  for (int rep = 0; rep < 16; rep++) {
    int i = rep * 4 + ty;
    tile[i][tx] = W[(size_t)(kt + i) * ncols + nt + tx];
  }
  __syncthreads();
#pragma unroll
  for (int rep = 0; rep < 16; rep++) {
    int i = rep * 4 + ty;
    int n = nt + i, k = kt + tx;
    float acc = tile[tx][i];
#pragma unroll
    for (int r = 0; r < 8; r++)
      acc += 2.0f * rLa[r] * sLb[r][i];  // LORA_SCALING = 2
    WT[(size_t)n * 1024 + k] = (__bf16)acc;
  }
}

__global__ __launch_bounds__(256)
void cast_x(const float* __restrict__ x, __bf16* __restrict__ o) {
  int i = blockIdx.x * 256 + threadIdx.x;
  float4 v = ((const float4*)x)[i];
  bf16x4 r = {(__bf16)v.x, (__bf16)v.y, (__bf16)v.z, (__bf16)v.w};
  ((bf16x4*)o)[i] = r;
}

// ---------------------------------------------------------------------------
// Fused QKV projection, swapped orientation: D[p][s] = sum_k WT[p][k] X[s][k].
// 128x128 tiles, BK=64, global_load_lds staging, XOR-swizzled LDS.
// Q channels (p<1024) pre-scaled by 0.125*LOG2E.
// V is written to vtb with keys PERMUTED within each 64-key chunk so the
// flash PV A-fragments are 16B-contiguous: key off (t=off>>4, qd=(off>>2)&3,
// r=off&3) stored at position (t>>1)*32 + qd*8 + (t&1)*4 + r.
// ---------------------------------------------------------------------------
__global__ __launch_bounds__(256)
void gemm_qkv(const __bf16* __restrict__ WT, const __bf16* __restrict__ X,
              const float* __restrict__ bias, __bf16* __restrict__ qk,
              __bf16* __restrict__ vtb) {
  const int K = 1024;
  __shared__ alignas(16) __bf16 As[128 * 64];
  __shared__ alignas(16) __bf16 Bs[128 * 64];
  const int tid = threadIdx.x;
  const int wave = tid >> 6, lane = tid & 63;
  const int wm = wave >> 1, wn = wave & 1;
  const int quad = lane >> 4, l15 = lane & 15;
  const int p0 = blockIdx.y * 128, s0 = blockIdx.x * 128;
  const int srow8 = lane >> 3, sc8 = lane & 7;
  const int sswz = sc8 ^ srow8;

  floatx4 acc[4][4] = {};

  for (int kb = 0; kb < K; kb += 64) {
    __syncthreads();
#pragma unroll
    for (int t = 0; t < 4; t++) {
      int rbase = (wave * 4 + t) * 8;
      int row = rbase + srow8;
      load_lds16(WT + (size_t)(p0 + row) * K + kb + sswz * 8, As + rbase * 64);
      load_lds16(X + (size_t)(s0 + row) * K + kb + sswz * 8, Bs + rbase * 64);
    }
    __syncthreads();
#pragma unroll
    for (int ks = 0; ks < 2; ks++) {
      bf16x8 af[4], bfv[4];
#pragma unroll
      for (int t = 0; t < 4; t++) {
        int ra = wm * 64 + t * 16 + l15;
        int rb = wn * 64 + t * 16 + l15;
        int ch = (ks * 4 + quad) ^ (l15 & 7);
        af[t]  = *(const bf16x8*)(As + ra * 64 + ch * 8);
        bfv[t] = *(const bf16x8*)(Bs + rb * 64 + ch * 8);
      }
#pragma unroll
      for (int mi = 0; mi < 4; mi++)
#pragma unroll
        for (int ni = 0; ni < 4; ni++)
          acc[mi][ni] = mfma16(af[mi], bfv[ni], acc[mi][ni]);
    }
  }

  const float qscale = (p0 < 1024) ? 0.125f * LOG2E : 1.0f;  // block-uniform
#pragma unroll
  for (int mi = 0; mi < 4; mi++) {
#pragma unroll
    for (int ni = 0; ni < 4; ni++) {
      int pb = p0 + wm * 64 + mi * 16 + quad * 4;  // channel base (mult of 4)
      int s  = s0 + wn * 64 + ni * 16 + l15;       // token
      int b = s >> 11, s2 = s & 2047;
      if (p0 < 2048) {  // q/k: uniform per block
        int part = pb >> 10, h = (pb & 1023) >> 6, dhb = pb & 63;
        bf16x4 o = {(__bf16)((acc[mi][ni][0] + bias[pb]) * qscale),
                    (__bf16)((acc[mi][ni][1] + bias[pb + 1]) * qscale),
                    (__bf16)((acc[mi][ni][2] + bias[pb + 2]) * qscale),
                    (__bf16)((acc[mi][ni][3] + bias[pb + 3]) * qscale)};
        *(bf16x4*)(qk + (size_t)part * 4194304 +
                   ((size_t)((b * 16 + h) * 2048 + s2)) * 64 + dhb) = o;
      } else {  // v -> v^T with per-chunk key permutation
        int h = (pb & 1023) >> 6, dhb = pb & 63;
        int off = s2 & 63, t = off >> 4, qd = (off >> 2) & 3, rr = off & 3;
        int ps2 = (s2 & ~63) | ((t >> 1) * 32 + qd * 8 + (t & 1) * 4 + rr);
#pragma unroll
        for (int r = 0; r < 4; r++)
          vtb[((size_t)((b * 16 + h) * 64 + dhb + r)) * 2048 + ps2] =
              (__bf16)(acc[mi][ni][r] + bias[pb + r]);
      }
    }
  }
}

// ---------------------------------------------------------------------------
// Output projection, 64x128 tile: grid (8, 64) = 512 blocks.  fp32 out + bias.
// ---------------------------------------------------------------------------
__global__ __launch_bounds__(256)
void gemm_proj(const __bf16* __restrict__ A, const __bf16* __restrict__ BT,
               const float* __restrict__ bias, float* __restrict__ Cout, int N) {
  const int K = 1024;
  __shared__ alignas(16) __bf16 As[64 * 64];
  __shared__ alignas(16) __bf16 Bs[128 * 64];
  const int tid = threadIdx.x;
  const int wave = tid >> 6, lane = tid & 63;
  const int wm = wave >> 1, wn = wave & 1;
  const int quad = lane >> 4, l15 = lane & 15;
  const int m0 = blockIdx.y * 64, n0 = blockIdx.x * 128;
  const int srow8 = lane >> 3, sc8 = lane & 7;
  const int sswz = sc8 ^ srow8;

  floatx4 acc[2][4] = {};

  for (int kb = 0; kb < K; kb += 64) {
    __syncthreads();
#pragma unroll
    for (int t = 0; t < 2; t++) {
      int rbase = (wave * 2 + t) * 8;
      load_lds16(A + (size_t)(m0 + rbase + srow8) * K + kb + sswz * 8,
                 As + rbase * 64);
    }
#pragma unroll
    for (int t = 0; t < 4; t++) {
      int rbase = (wave * 4 + t) * 8;
      load_lds16(BT + (size_t)(n0 + rbase + srow8) * K + kb + sswz * 8,
                 Bs + rbase * 64);
    }
    __syncthreads();
#pragma unroll
    for (int ks = 0; ks < 2; ks++) {
      bf16x8 af[2], bfv[4];
      int ch = (ks * 4 + quad) ^ (l15 & 7);
#pragma unroll
      for (int t = 0; t < 2; t++)
        af[t] = *(const bf16x8*)(As + (wm * 32 + t * 16 + l15) * 64 + ch * 8);
#pragma unroll
      for (int t = 0; t < 4; t++)
        bfv[t] = *(const bf16x8*)(Bs + (wn * 64 + t * 16 + l15) * 64 + ch * 8);
#pragma unroll
      for (int mi = 0; mi < 2; mi++)
#pragma unroll
        for (int ni = 0; ni < 4; ni++)
          acc[mi][ni] = mfma16(af[mi], bfv[ni], acc[mi][ni]);
    }
  }

#pragma unroll
  for (int mi = 0; mi < 2; mi++)
#pragma unroll
    for (int ni = 0; ni < 4; ni++) {
      int n = n0 + wn * 64 + ni * 16 + l15;
#pragma unroll
      for (int r = 0; r < 4; r++) {
        int m = m0 + wm * 32 + mi * 16 + quad * 4 + r;
        Cout[(size_t)m * N + n] = acc[mi][ni][r] + bias[n];
      }
    }
}

// ---------------------------------------------------------------------------
// Causal flash attention v17: v13 chassis, chain cuts only.
// v16 post-mortem: one-barrier + in-body QK forced vmcnt(0) per iter and
// 96 VGPR -> regressed.  v13 (2 barriers, counted vmcnt, QK at top) stays.
// v17 = v13 + three ISOLATED fixes, structure untouched:
//  1. vmcnt off-by-one: v13's per-chunk am_nxt load entered the vm queue
//     right before vmcnt(4), forcing an exposed L2 round trip per chunk.
//     The per-chunk amask load/ballot is replaced by a one-time int4
//     pre-scan (<=8 loads, over-scan-safe: reads stay inside row b); loop
//     queue now holds exactly the 4 stage DMAs -> vmcnt(4) never blocks on
//     fresh loads and stage(c) has a full iteration to land.
//  2. Fast-path softmax has NO cross-lane ops: defer check uses the in-lane
//     max (all lanes' in-lane maxes <= mrun+8 => all row maxes too, via
//     __all); the 2 serial max-shfls run only on the (never-taken) rescale
//     path.  In-lane max written as fmax triples -> v_max3_f32 (T17).
//  3. lrun kept as per-quad partial; cross-quad sum (2 shfls) deferred to
//     the epilogue (once per strip instead of per chunk).
// ---------------------------------------------------------------------------
__global__ __launch_bounds__(256)
void flash_attn(const __bf16* __restrict__ q, const __bf16* __restrict__ k,
                const __bf16* __restrict__ vt, const int* __restrict__ amask,
                __bf16* __restrict__ ctx) {
  const int S = 2048;
  __shared__ alignas(16) __bf16 Ks[2][64 * 64];
  __shared__ alignas(16) __bf16 Vs[2][64 * 64];
  const int bid = blockIdx.x;
  const int jb = 31 - (bid >> 5);    // strip, longest first
  const int bh = bid & 31;           // bh%8 = XCD -> per-head K/V L2 locality
  const int b = bh >> 4, h = bh & 15;
  const int wave = threadIdx.x >> 6, lane = threadIdx.x & 63;
  const int quad = lane >> 4, l15 = lane & 15;
  const int srow8 = lane >> 3, sc8 = lane & 7;
  const int sswz = sc8 ^ srow8;
  const int Q0 = jb * 64;
  const int qrow = Q0 + wave * 16 + l15;  // this wave's query rows

  const __bf16* qp  = q  + (size_t)bh * S * 64;
  const __bf16* kp0 = k  + (size_t)bh * S * 64;
  const __bf16* vp0 = vt + (size_t)bh * 64 * S;

  // one-time padding pre-scan (int4 = 4 chunks per lane-load, <=8 iters).
  // Over-scan past (jb+1)*64 stays inside row b (S=2048) -> safe; it can
  // only set padded=true spuriously (slow path is still correct per chunk).
  int anyp = 0;
  const int npre = (jb + 4) >> 2;
  for (int it = 0; it < npre; it++) {
    int4 v = *(const int4*)(amask + b * S + it * 256 + lane * 4);
    anyp |= (v.x == 0) | (v.y == 0) | (v.z == 0) | (v.w == 0);
  }
  const bool padded = (__ballot(anyp) != 0ull);  // block-uniform

  // Q fragments (issued before STAGE(0) -> drained by the first vmcnt)
  bf16x8 qf[2];
#pragma unroll
  for (int ks = 0; ks < 2; ks++)
    qf[ks] = *(const bf16x8*)(qp + (size_t)qrow * 64 + ks * 32 + quad * 8);

  // stage chunk cc into buffer bb: each wave stages 16 rows of K and V.
  // K chunk rows = keys (contiguous 4096 elems); V chunk rows = dh
  // (row stride S).  XOR pre-swizzled global source, linear LDS dest.
  auto STAGE = [&](int bb, int cc) {
#pragma unroll
    for (int t = 0; t < 2; t++) {
      int rbase = (wave * 2 + t) * 8;
      load_lds16(kp0 + (size_t)cc * 4096 + (size_t)(rbase + srow8) * 64 +
                     sswz * 8,
                 &Ks[bb][rbase * 64]);
    }
#pragma unroll
    for (int t = 0; t < 2; t++) {
      int rbase = (wave * 2 + t) * 8;
      load_lds16(vp0 + (size_t)(rbase + srow8) * S + cc * 64 + sswz * 8,
                 &Vs[bb][rbase * 64]);
    }
  };

  STAGE(0, 0);

  float mrun = 0.0f, lrun = 0.0f;  // lrun = per-quad PARTIAL sum
  floatx4 oacc[4] = {};  // [dh-tile]; col(l15)=q, row(quad*4+r)=dh

  for (int c = 0; c <= jb; c++) {
    const int cur = c & 1;
    if (c < jb) {
      STAGE(cur ^ 1, c + 1);
      // queue = [stage(c) x4 (one iter old), stage(c+1) x4]; drain stage(c)
      asm volatile("s_waitcnt vmcnt(4)" ::: "memory");
    } else {
      asm volatile("s_waitcnt vmcnt(0)" ::: "memory");
    }
    __builtin_amdgcn_s_barrier();          // chunk c data visible to all
    __builtin_amdgcn_sched_barrier(0);     // no ds_read hoist above barrier

    // S^T = K.Q^T: C col(l15)=q, row(quad*4+r)=key
    floatx4 st[4] = {};
    __builtin_amdgcn_s_setprio(1);
#pragma unroll
    for (int ks = 0; ks < 2; ks++) {
      const int ch = (ks * 4 + quad) ^ (l15 & 7);
      bf16x8 kf[4];
#pragma unroll
      for (int nt = 0; nt < 4; nt++)
        kf[nt] = *(const bf16x8*)(&Ks[cur][(nt * 16 + l15) * 64 + ch * 8]);
#pragma unroll
      for (int nt = 0; nt < 4; nt++)
        st[nt] = mfma16(kf[nt], qf[ks], st[nt]);
    }
    __builtin_amdgcn_s_setprio(0);

    // masking: fast path = causal diagonal only (padded is block-uniform)
    if (padded) {
      int am_c = amask[b * S + c * 64 + lane];  // rare path, latency ok
      unsigned long long pm = __ballot(am_c == 0);
#pragma unroll
      for (int nt = 0; nt < 4; nt++) {
        int kl = nt * 16 + quad * 4;
#pragma unroll
        for (int r = 0; r < 4; r++) {
          bool pad = (pm >> (kl + r)) & 1ull;
          bool masked = pad || ((c == jb) && (kl + r > wave * 16 + l15));
          st[nt][r] = masked ? MASKVAL : st[nt][r];
        }
      }
    } else if (c == jb) {  // diagonal chunk: local causal mask only
#pragma unroll
      for (int nt = 0; nt < 4; nt++) {
        int kl = nt * 16 + quad * 4;
#pragma unroll
        for (int r = 0; r < 4; r++) {
          bool masked = kl + r > wave * 16 + l15;
          st[nt][r] = masked ? MASKVAL : st[nt][r];
        }
      }
    }

    // shuffle-free fast-path softmax (log2 domain, per q = l15)
    float t0 = max3f(st[0][0], st[0][1], st[0][2]);
    float t1 = max3f(st[0][3], st[1][0], st[1][1]);
    float t2 = max3f(st[1][2], st[1][3], st[2][0]);
    float t3 = max3f(st[2][1], st[2][2], st[2][3]);
    float t4 = max3f(st[3][0], st[3][1], st[3][2]);
    float inm = fmaxf(max3f(t0, t1, t2), max3f(t3, t4, st[3][3]));
#pragma unroll
    for (int nt = 0; nt < 4; nt++)
#pragma unroll
      for (int r = 0; r < 4; r++)
        st[nt][r] = exp2f(st[nt][r] - mrun);  // p vs mrun_old, exact
    float ssum = (((st[0][0] + st[0][1]) + (st[0][2] + st[0][3])) +
                  ((st[1][0] + st[1][1]) + (st[1][2] + st[1][3]))) +
                 (((st[2][0] + st[2][1]) + (st[2][2] + st[2][3])) +
                  ((st[3][0] + st[3][1]) + (st[3][2] + st[3][3])));
    if (!__all(inm - mrun <= 8.0f)) {  // rare rescale (wave-uniform)
      float rm = fmaxf(inm, __shfl_xor(inm, 16, 64));
      rm = fmaxf(rm, __shfl_xor(rm, 32, 64));
      float mnew = fmaxf(mrun, rm);
      float al = exp2f(mrun - mnew);
      mrun = mnew;
      lrun *= al;
      ssum *= al;
#pragma unroll
      for (int nt = 0; nt < 4; nt++)
#pragma unroll
        for (int r = 0; r < 4; r++) st[nt][r] *= al;
#pragma unroll
      for (int nd = 0; nd < 4; nd++)
#pragma unroll
        for (int r = 0; r < 4; r++) oacc[nd][r] *= al;
    }
    lrun += ssum;

    // pack P tiles (B-operand == C-layout)
    bf16x4 pB[4];
#pragma unroll
    for (int nt = 0; nt < 4; nt++) {
      bf16x4 pk = {(__bf16)st[nt][0], (__bf16)st[nt][1],
                   (__bf16)st[nt][2], (__bf16)st[nt][3]};
      pB[nt] = pk;
    }

    // O^T += V^T P^T ; one 16B V frag feeds key-subtiles 2tp and 2tp+1
    __builtin_amdgcn_s_setprio(1);
#pragma unroll
    for (int tp = 0; tp < 2; tp++) {
      const int chv = (tp * 4 + quad) ^ (l15 & 7);
#pragma unroll
      for (int nd = 0; nd < 4; nd++) {
        bf16x8 v8 =
            *(const bf16x8*)(&Vs[cur][(nd * 16 + l15) * 64 + chv * 8]);
        bf16x4 vA0 = {v8[0], v8[1], v8[2], v8[3]};
        bf16x4 vA1 = {v8[4], v8[5], v8[6], v8[7]};
        oacc[nd] = mfma_pv(vA0, pB[2 * tp], oacc[nd]);
        oacc[nd] = mfma_pv(vA1, pB[2 * tp + 1], oacc[nd]);
      }
    }
    __builtin_amdgcn_s_setprio(0);

    __builtin_amdgcn_s_barrier();  // all waves done reading buf cur
  }

  // deferred cross-quad l reduction (once per strip instead of per chunk)
  lrun += __shfl_xor(lrun, 16, 64);
  lrun += __shfl_xor(lrun, 32, 64);

  // epilogue: direct normalize + store (no merge).  1/lrun exact under
  // defer-max (P and lrun share the same mrun reference).
  const float linv = 1.0f / lrun;
#pragma unroll
  for (int nd = 0; nd < 4; nd++) {
    bf16x4 o = {(__bf16)(oacc[nd][0] * linv), (__bf16)(oacc[nd][1] * linv),
                (__bf16)(oacc[nd][2] * linv), (__bf16)(oacc[nd][3] * linv)};
    *(bf16x4*)(ctx + ((size_t)(b * 2048 + qrow)) * 1024 + h * 64 + nd * 16 +
               quad * 4) = o;
  }
}

// ---------------------------------------------------------------------------
extern "C" void kernel_launch(void* const* d_in, const int* in_sizes, int n_in,
                              void* d_out, int out_size, void* d_ws, size_t ws_size,
                              hipStream_t stream) {
  const float* x  = (const float*)d_in[0];
  const int*   am = (const int*)d_in[1];
  const float* Wq = (const float*)d_in[2];
  const float* bq = (const float*)d_in[3];
  const float* Aq = (const float*)d_in[4];
  const float* Bq = (const float*)d_in[5];
  const float* Wp = (const float*)d_in[6];
  const float* bp = (const float*)d_in[7];
  const float* Ap = (const float*)d_in[8];
  const float* Bp = (const float*)d_in[9];

  __bf16* wqkvT = (__bf16*)d_ws;                       // [3072][1024]
  __bf16* wpT   = wqkvT + (size_t)3072 * 1024;         // [1024][1024]
  __bf16* xbf   = wpT   + (size_t)1024 * 1024;         // [4096][1024]
  __bf16* qbuf  = xbf   + (size_t)4096 * 1024;         // [2][16][2048][64] (+kbuf)
  __bf16* vtbuf = qbuf  + (size_t)2 * 4194304;         // [2][16][64][2048] permuted
  __bf16* ctxb  = vtbuf + (size_t)4194304;             // [4096][1024]

  fold_wt2<<<dim3(64, 16), 256, 0, stream>>>(Wq, Aq, Bq, wqkvT,
                                             Wp, Ap, Bp, wpT);
  cast_x<<<4096, 256, 0, stream>>>(x, xbf);

  gemm_qkv<<<dim3(32, 24), 256, 0, stream>>>(wqkvT, xbf, bq, qbuf, vtbuf);
  flash_attn<<<1024, 256, 0, stream>>>(qbuf, qbuf + 4194304, vtbuf, am, ctxb);
  gemm_proj<<<dim3(8, 64), 256, 0, stream>>>(ctxb, wpT, bp, (float*)d_out, 1024);
}

// Round 7
// 187.191 us; speedup vs baseline: 1.1265x; 1.0889x over previous
//
#include <hip/hip_runtime.h>
#include <hip/hip_bf16.h>

#define LOG2E 1.4426950408889634f
// reference: mask(-1e9) BEFORE scale(/8); log2e folded into Q pre-scale
#define MASKVAL (-1.25e8f * LOG2E)

typedef __bf16 bf16x8 __attribute__((ext_vector_type(8)));
typedef __bf16 bf16x4 __attribute__((ext_vector_type(4)));
typedef short  shortx4 __attribute__((ext_vector_type(4)));
typedef float  floatx4 __attribute__((ext_vector_type(4)));

__device__ __forceinline__ floatx4 mfma16(bf16x8 a, bf16x8 b, floatx4 c) {
  return __builtin_amdgcn_mfma_f32_16x16x32_bf16(a, b, c, 0, 0, 0);
}

// 16x16x16 bf16 MFMA: B-operand layout (n=l15, k=quad*4+i) == S^T C-tile
// layout -> P feeds PV with zero cross-lane transforms.
__device__ __forceinline__ floatx4 mfma_pv(bf16x4 a, bf16x4 b, floatx4 c) {
#if __has_builtin(__builtin_amdgcn_mfma_f32_16x16x16_bf16)
  return __builtin_amdgcn_mfma_f32_16x16x16_bf16(a, b, c, 0, 0, 0);
#else
  shortx4 as, bs;
  __builtin_memcpy(&as, &a, 8);
  __builtin_memcpy(&bs, &b, 8);
  return __builtin_amdgcn_mfma_f32_16x16x16bf16_1k(as, bs, c, 0, 0, 0);
#endif
}

// async global->LDS, 16B per lane. Dest = wave-uniform base + lane*16.
__device__ __forceinline__ void load_lds16(const __bf16* g, __bf16* l) {
  __builtin_amdgcn_global_load_lds(
      (const __attribute__((address_space(1))) void*)g,
      (__attribute__((address_space(3))) void*)l, 16, 0, 0);
}

// encourage v_max3_f32 fusion
__device__ __forceinline__ float max3f(float a, float b, float c) {
  return fmaxf(a, fmaxf(b, c));
}

// ---------------------------------------------------------------------------
// Fold LoRA into weights, emit W_eff^T bf16 [ncols][1024].  Both weight sets
// in one launch: blockIdx.x < 48 -> qkv (ncols 3072), else proj (ncols 1024).
// ---------------------------------------------------------------------------
__global__ __launch_bounds__(256)
void fold_wt2(const float* __restrict__ Wq, const float* __restrict__ Aq,
              const float* __restrict__ Bq, __bf16* __restrict__ WTq,
              const float* __restrict__ Wp, const float* __restrict__ Ap,
              const float* __restrict__ Bp, __bf16* __restrict__ WTp) {
  __shared__ float tile[64][65];
  __shared__ float sLb[8][64];
  const int bx = blockIdx.x;
  const bool isQ = bx < 48;
  const float* W  = isQ ? Wq : Wp;
  const float* La = isQ ? Aq : Ap;
  const float* Lb = isQ ? Bq : Bp;
  __bf16* WT = isQ ? WTq : WTp;
  const int ncols = isQ ? 3072 : 1024;
  const int nt = (isQ ? bx : bx - 48) * 64;
  const int kt = blockIdx.y * 64;
  const int tid = threadIdx.x;
  const int tx = tid & 63, ty = tid >> 6;

  float rLa[8];
  *(float4*)&rLa[0] = *(const float4*)(La + (size_t)(kt + tx) * 8);
  *(float4*)&rLa[4] = *(const float4*)(La + (size_t)(kt + tx) * 8 + 4);

#pragma unroll
  for (int rep = 0; rep < 2; rep++) {
    int idx = tid + rep * 256;
    sLb[idx >> 6][idx & 63] = Lb[(size_t)(idx >> 6) * ncols + nt + (idx & 63)];
  }
#pragma unroll
  for (int rep = 0; rep < 16; rep++) {
    int i = rep * 4 + ty;
    tile[i][tx] = W[(size_t)(kt + i) * ncols + nt + tx];
  }
  __syncthreads();
#pragma unroll
  for (int rep = 0; rep < 16; rep++) {
    int i = rep * 4 + ty;
    int n = nt + i, k = kt + tx;
    float acc = tile[tx][i];
#pragma unroll
    for (int r = 0; r < 8; r++)
      acc += 2.0f * rLa[r] * sLb[r][i];  // LORA_SCALING = 2
    WT[(size_t)n * 1024 + k] = (__bf16)acc;
  }
}

__global__ __launch_bounds__(256)
void cast_x(const float* __restrict__ x, __bf16* __restrict__ o) {
  int i = blockIdx.x * 256 + threadIdx.x;
  float4 v = ((const float4*)x)[i];
  bf16x4 r = {(__bf16)v.x, (__bf16)v.y, (__bf16)v.z, (__bf16)v.w};
  ((bf16x4*)o)[i] = r;
}

// ---------------------------------------------------------------------------
// Fused QKV projection v2: D[p][s] = sum_k WT[p][k] X[s][k], 128x128 tiles,
// BK=64, global_load_lds staging.
// v1 post-mortem (61.5us, MfmaUtil 15%, VALU 21%, HBM 12% -- nothing busy):
//  (a) naive 2-phase K-loop: the sync after STAGE emits s_waitcnt vmcnt(0),
//      a full drain of the just-issued DMAs EVERY iter (16 iters, short K ->
//      poorly amortized).  Fix: LDS double-buffer + counted vmcnt(8) + raw
//      s_barrier (the proven flash v13 pattern): stage(k+1) flies under
//      compute(k); only the last iter drains.
//  (b) scattered epilogue: V wrote 64 scalar 2B stores/wave at 4KB stride
//      (64 lines per instr); q/k wrote 8B stores at 128B lane stride.  Fix:
//      stage the output tile in the (now free) 64KB LDS -- q/k as
//      [token][ch], V as [ch][permuted-token] with the flash PV permutation
//      applied at LDS-write time -- then write out lane-contiguous bf16x8:
//      q/k 1KB contiguous per instr, V 4x256B runs per instr.
// Q channels (p<1024) pre-scaled by 0.125*LOG2E.
// ---------------------------------------------------------------------------
__global__ __launch_bounds__(256)
void gemm_qkv(const __bf16* __restrict__ WT, const __bf16* __restrict__ X,
              const float* __restrict__ bias, __bf16* __restrict__ qk,
              __bf16* __restrict__ vtb) {
  const int K = 1024;
  __shared__ alignas(16) __bf16 smem[32768];  // 64 KB: A0|A1|B0|B1
  const int tid = threadIdx.x;
  const int wave = tid >> 6, lane = tid & 63;
  const int wm = wave >> 1, wn = wave & 1;
  const int quad = lane >> 4, l15 = lane & 15;
  const int p0 = blockIdx.y * 128, s0 = blockIdx.x * 128;
  const int srow8 = lane >> 3, sc8 = lane & 7;
  const int sswz = sc8 ^ srow8;

  auto STAGE = [&](int bb, int kb) {
    __bf16* Ab = smem + bb * 8192;
    __bf16* Bb = smem + 16384 + bb * 8192;
#pragma unroll
    for (int t = 0; t < 4; t++) {
      int rbase = (wave * 4 + t) * 8;
      int row = rbase + srow8;
      load_lds16(WT + (size_t)(p0 + row) * K + kb + sswz * 8, Ab + rbase * 64);
      load_lds16(X + (size_t)(s0 + row) * K + kb + sswz * 8, Bb + rbase * 64);
    }
  };

  floatx4 acc[4][4] = {};
  STAGE(0, 0);

  for (int it = 0; it < 16; it++) {
    const int cur = it & 1;
    if (it < 15) {
      STAGE(cur ^ 1, (it + 1) * 64);
      // queue = [stage(it) x8 (one iter old), stage(it+1) x8]; drain stage(it)
      asm volatile("s_waitcnt vmcnt(8)" ::: "memory");
    } else {
      asm volatile("s_waitcnt vmcnt(0)" ::: "memory");
    }
    __builtin_amdgcn_s_barrier();
    __builtin_amdgcn_sched_barrier(0);
    const __bf16* Ac = smem + cur * 8192;
    const __bf16* Bc = smem + 16384 + cur * 8192;
#pragma unroll
    for (int ks = 0; ks < 2; ks++) {
      bf16x8 af[4], bfv[4];
#pragma unroll
      for (int t = 0; t < 4; t++) {
        int ra = wm * 64 + t * 16 + l15;
        int rb = wn * 64 + t * 16 + l15;
        int ch = (ks * 4 + quad) ^ (l15 & 7);
        af[t]  = *(const bf16x8*)(Ac + ra * 64 + ch * 8);
        bfv[t] = *(const bf16x8*)(Bc + rb * 64 + ch * 8);
      }
#pragma unroll
      for (int mi = 0; mi < 4; mi++)
#pragma unroll
        for (int ni = 0; ni < 4; ni++)
          acc[mi][ni] = mfma16(af[mi], bfv[ni], acc[mi][ni]);
    }
    __builtin_amdgcn_s_barrier();  // all waves done with buf cur
  }

  // ---- coalesced epilogue via LDS transpose (64KB smem now free) ----
  // tile rows stride 136 elems (272B = 17x16B: keeps b64/b128 alignment)
  __bf16* ep = smem;
  const int b = s0 >> 11, s2b = s0 & 2047;  // tile fully inside one batch

  if (p0 < 2048) {  // ---- q/k: LDS [token][ch 0..127] -> [tok][dh] rows ----
    const float qscale = (p0 < 1024) ? 0.125f * LOG2E : 1.0f;
#pragma unroll
    for (int mi = 0; mi < 4; mi++) {
      int ch0 = wm * 64 + mi * 16 + quad * 4;
      float4 b4 = *(const float4*)(bias + p0 + ch0);
#pragma unroll
      for (int ni = 0; ni < 4; ni++) {
        int tl = wn * 64 + ni * 16 + l15;
        bf16x4 o = {(__bf16)((acc[mi][ni][0] + b4.x) * qscale),
                    (__bf16)((acc[mi][ni][1] + b4.y) * qscale),
                    (__bf16)((acc[mi][ni][2] + b4.z) * qscale),
                    (__bf16)((acc[mi][ni][3] + b4.w) * qscale)};
        *(bf16x4*)(ep + tl * 136 + ch0) = o;
      }
    }
    __syncthreads();
    const int part = p0 >> 10;
    const int h0 = (p0 & 1023) >> 6;         // tile = heads h0, h0+1
    const int hs = wave & 1, tb = (wave >> 1) * 64;
    __bf16* outp = qk + (size_t)part * 4194304 +
                   ((size_t)((b * 16 + h0 + hs) * 2048 + s2b)) * 64;
#pragma unroll
    for (int j = 0; j < 8; j++) {
      int tok = tb + j * 8 + (lane >> 3);
      int dh = (lane & 7) * 8;
      bf16x8 v = *(const bf16x8*)(ep + tok * 136 + hs * 64 + dh);
      *(bf16x8*)(outp + (size_t)tok * 64 + dh) = v;   // 1KB contig / instr
    }
  } else {  // ---- v: LDS [ch][permuted tok] -> [dh] rows of 256B ----
#pragma unroll
    for (int mi = 0; mi < 4; mi++) {
      int ch0 = wm * 64 + mi * 16 + quad * 4;
      float4 b4 = *(const float4*)(bias + p0 + ch0);
#pragma unroll
      for (int ni = 0; ni < 4; ni++) {
        int tl = wn * 64 + ni * 16 + l15;
        int off = tl & 63, t = off >> 4, qd = (off >> 2) & 3, rr = off & 3;
        int ptl = (tl & 64) | ((t >> 1) * 32 + qd * 8 + (t & 1) * 4 + rr);
        ep[(ch0 + 0) * 136 + ptl] = (__bf16)(acc[mi][ni][0] + b4.x);
        ep[(ch0 + 1) * 136 + ptl] = (__bf16)(acc[mi][ni][1] + b4.y);
        ep[(ch0 + 2) * 136 + ptl] = (__bf16)(acc[mi][ni][2] + b4.z);
        ep[(ch0 + 3) * 136 + ptl] = (__bf16)(acc[mi][ni][3] + b4.w);
      }
    }
    __syncthreads();
    const int h0 = (p0 & 1023) >> 6;
#pragma unroll
    for (int j = 0; j < 8; j++) {
      int ch = wave * 32 + j * 4 + (lane >> 4);
      int to = (lane & 15) * 8;
      bf16x8 v = *(const bf16x8*)(ep + ch * 136 + to);
      int h = h0 + (ch >> 6), dh = ch & 63;
      *(bf16x8*)(vtb + ((size_t)((b * 16 + h) * 64 + dh)) * 2048 + s2b + to) =
          v;  // 4 x 256B runs / instr
    }
  }
}

// ---------------------------------------------------------------------------
// Output projection v2, 64x128 tile, grid (8, 64): same counted-vmcnt LDS
// double-buffer as gemm_qkv (6 DMAs/stage -> vmcnt(6)).  fp32 out + bias.
// ---------------------------------------------------------------------------
__global__ __launch_bounds__(256)
void gemm_proj(const __bf16* __restrict__ A, const __bf16* __restrict__ BT,
               const float* __restrict__ bias, float* __restrict__ Cout, int N) {
  const int K = 1024;
  __shared__ alignas(16) __bf16 smem[24576];  // 48 KB: A0|A1|B0|B1
  const int tid = threadIdx.x;
  const int wave = tid >> 6, lane = tid & 63;
  const int wm = wave >> 1, wn = wave & 1;
  const int quad = lane >> 4, l15 = lane & 15;
  const int m0 = blockIdx.y * 64, n0 = blockIdx.x * 128;
  const int srow8 = lane >> 3, sc8 = lane & 7;
  const int sswz = sc8 ^ srow8;

  auto STAGE = [&](int bb, int kb) {
    __bf16* Ab = smem + bb * 4096;
    __bf16* Bb = smem + 8192 + bb * 8192;
#pragma unroll
    for (int t = 0; t < 2; t++) {
      int rbase = (wave * 2 + t) * 8;
      load_lds16(A + (size_t)(m0 + rbase + srow8) * K + kb + sswz * 8,
                 Ab + rbase * 64);
    }
#pragma unroll
    for (int t = 0; t < 4; t++) {
      int rbase = (wave * 4 + t) * 8;
      load_lds16(BT + (size_t)(n0 + rbase + srow8) * K + kb + sswz * 8,
                 Bb + rbase * 64);
    }
  };

  floatx4 acc[2][4] = {};
  STAGE(0, 0);

  for (int it = 0; it < 16; it++) {
    const int cur = it & 1;
    if (it < 15) {
      STAGE(cur ^ 1, (it + 1) * 64);
      asm volatile("s_waitcnt vmcnt(6)" ::: "memory");
    } else {
      asm volatile("s_waitcnt vmcnt(0)" ::: "memory");
    }
    __builtin_amdgcn_s_barrier();
    __builtin_amdgcn_sched_barrier(0);
    const __bf16* Ac = smem + cur * 4096;
    const __bf16* Bc = smem + 8192 + cur * 8192;
#pragma unroll
    for (int ks = 0; ks < 2; ks++) {
      bf16x8 af[2], bfv[4];
      int ch = (ks * 4 + quad) ^ (l15 & 7);
#pragma unroll
      for (int t = 0; t < 2; t++)
        af[t] = *(const bf16x8*)(Ac + (wm * 32 + t * 16 + l15) * 64 + ch * 8);
#pragma unroll
      for (int t = 0; t < 4; t++)
        bfv[t] = *(const bf16x8*)(Bc + (wn * 64 + t * 16 + l15) * 64 + ch * 8);
#pragma unroll
      for (int mi = 0; mi < 2; mi++)
#pragma unroll
        for (int ni = 0; ni < 4; ni++)
          acc[mi][ni] = mfma16(af[mi], bfv[ni], acc[mi][ni]);
    }
    __builtin_amdgcn_s_barrier();
  }

#pragma unroll
  for (int mi = 0; mi < 2; mi++)
#pragma unroll
    for (int ni = 0; ni < 4; ni++) {
      int n = n0 + wn * 64 + ni * 16 + l15;
#pragma unroll
      for (int r = 0; r < 4; r++) {
        int m = m0 + wm * 32 + mi * 16 + quad * 4 + r;
        Cout[(size_t)m * N + n] = acc[mi][ni][r] + bias[n];
      }
    }
}

// ---------------------------------------------------------------------------
// Causal flash attention v17 (unchanged from round 6 -- it moved below
// gemm_qkv): v13 chassis + pre-scanned padding + shuffle-free fast-path
// softmax + per-quad partial lrun.
// ---------------------------------------------------------------------------
__global__ __launch_bounds__(256)
void flash_attn(const __bf16* __restrict__ q, const __bf16* __restrict__ k,
                const __bf16* __restrict__ vt, const int* __restrict__ amask,
                __bf16* __restrict__ ctx) {
  const int S = 2048;
  __shared__ alignas(16) __bf16 Ks[2][64 * 64];
  __shared__ alignas(16) __bf16 Vs[2][64 * 64];
  const int bid = blockIdx.x;
  const int jb = 31 - (bid >> 5);    // strip, longest first
  const int bh = bid & 31;           // bh%8 = XCD -> per-head K/V L2 locality
  const int b = bh >> 4, h = bh & 15;
  const int wave = threadIdx.x >> 6, lane = threadIdx.x & 63;
  const int quad = lane >> 4, l15 = lane & 15;
  const int srow8 = lane >> 3, sc8 = lane & 7;
  const int sswz = sc8 ^ srow8;
  const int Q0 = jb * 64;
  const int qrow = Q0 + wave * 16 + l15;  // this wave's query rows

  const __bf16* qp  = q  + (size_t)bh * S * 64;
  const __bf16* kp0 = k  + (size_t)bh * S * 64;
  const __bf16* vp0 = vt + (size_t)bh * 64 * S;

  // one-time padding pre-scan (int4 = 4 chunks per lane-load, <=8 iters).
  int anyp = 0;
  const int npre = (jb + 4) >> 2;
  for (int it = 0; it < npre; it++) {
    int4 v = *(const int4*)(amask + b * S + it * 256 + lane * 4);
    anyp |= (v.x == 0) | (v.y == 0) | (v.z == 0) | (v.w == 0);
  }
  const bool padded = (__ballot(anyp) != 0ull);  // block-uniform

  // Q fragments (issued before STAGE(0) -> drained by the first vmcnt)
  bf16x8 qf[2];
#pragma unroll
  for (int ks = 0; ks < 2; ks++)
    qf[ks] = *(const bf16x8*)(qp + (size_t)qrow * 64 + ks * 32 + quad * 8);

  auto STAGE = [&](int bb, int cc) {
#pragma unroll
    for (int t = 0; t < 2; t++) {
      int rbase = (wave * 2 + t) * 8;
      load_lds16(kp0 + (size_t)cc * 4096 + (size_t)(rbase + srow8) * 64 +
                     sswz * 8,
                 &Ks[bb][rbase * 64]);
    }
#pragma unroll
    for (int t = 0; t < 2; t++) {
      int rbase = (wave * 2 + t) * 8;
      load_lds16(vp0 + (size_t)(rbase + srow8) * S + cc * 64 + sswz * 8,
                 &Vs[bb][rbase * 64]);
    }
  };

  STAGE(0, 0);

  float mrun = 0.0f, lrun = 0.0f;  // lrun = per-quad PARTIAL sum
  floatx4 oacc[4] = {};  // [dh-tile]; col(l15)=q, row(quad*4+r)=dh

  for (int c = 0; c <= jb; c++) {
    const int cur = c & 1;
    if (c < jb) {
      STAGE(cur ^ 1, c + 1);
      asm volatile("s_waitcnt vmcnt(4)" ::: "memory");
    } else {
      asm volatile("s_waitcnt vmcnt(0)" ::: "memory");
    }
    __builtin_amdgcn_s_barrier();          // chunk c data visible to all
    __builtin_amdgcn_sched_barrier(0);     // no ds_read hoist above barrier

    // S^T = K.Q^T: C col(l15)=q, row(quad*4+r)=key
    floatx4 st[4] = {};
    __builtin_amdgcn_s_setprio(1);
#pragma unroll
    for (int ks = 0; ks < 2; ks++) {
      const int ch = (ks * 4 + quad) ^ (l15 & 7);
      bf16x8 kf[4];
#pragma unroll
      for (int nt = 0; nt < 4; nt++)
        kf[nt] = *(const bf16x8*)(&Ks[cur][(nt * 16 + l15) * 64 + ch * 8]);
#pragma unroll
      for (int nt = 0; nt < 4; nt++)
        st[nt] = mfma16(kf[nt], qf[ks], st[nt]);
    }
    __builtin_amdgcn_s_setprio(0);

    // masking: fast path = causal diagonal only (padded is block-uniform)
    if (padded) {
      int am_c = amask[b * S + c * 64 + lane];  // rare path, latency ok
      unsigned long long pm = __ballot(am_c == 0);
#pragma unroll
      for (int nt = 0; nt < 4; nt++) {
        int kl = nt * 16 + quad * 4;
#pragma unroll
        for (int r = 0; r < 4; r++) {
          bool pad = (pm >> (kl + r)) & 1ull;
          bool masked = pad || ((c == jb) && (kl + r > wave * 16 + l15));
          st[nt][r] = masked ? MASKVAL : st[nt][r];
        }
      }
    } else if (c == jb) {  // diagonal chunk: local causal mask only
#pragma unroll
      for (int nt = 0; nt < 4; nt++) {
        int kl = nt * 16 + quad * 4;
#pragma unroll
        for (int r = 0; r < 4; r++) {
          bool masked = kl + r > wave * 16 + l15;
          st[nt][r] = masked ? MASKVAL : st[nt][r];
        }
      }
    }

    // shuffle-free fast-path softmax (log2 domain, per q = l15)
    float t0 = max3f(st[0][0], st[0][1], st[0][2]);
    float t1 = max3f(st[0][3], st[1][0], st[1][1]);
    float t2 = max3f(st[1][2], st[1][3], st[2][0]);
    float t3 = max3f(st[2][1], st[2][2], st[2][3]);
    float t4 = max3f(st[3][0], st[3][1], st[3][2]);
    float inm = fmaxf(max3f(t0, t1, t2), max3f(t3, t4, st[3][3]));
#pragma unroll
    for (int nt = 0; nt < 4; nt++)
#pragma unroll
      for (int r = 0; r < 4; r++)
        st[nt][r] = exp2f(st[nt][r] - mrun);  // p vs mrun_old, exact
    float ssum = (((st[0][0] + st[0][1]) + (st[0][2] + st[0][3])) +
                  ((st[1][0] + st[1][1]) + (st[1][2] + st[1][3]))) +
                 (((st[2][0] + st[2][1]) + (st[2][2] + st[2][3])) +
                  ((st[3][0] + st[3][1]) + (st[3][2] + st[3][3])));
    if (!__all(inm - mrun <= 8.0f)) {  // rare rescale (wave-uniform)
      float rm = fmaxf(inm, __shfl_xor(inm, 16, 64));
      rm = fmaxf(rm, __shfl_xor(rm, 32, 64));
      float mnew = fmaxf(mrun, rm);
      float al = exp2f(mrun - mnew);
      mrun = mnew;
      lrun *= al;
      ssum *= al;
#pragma unroll
      for (int nt = 0; nt < 4; nt++)
#pragma unroll
        for (int r = 0; r < 4; r++) st[nt][r] *= al;
#pragma unroll
      for (int nd = 0; nd < 4; nd++)
#pragma unroll
        for (int r = 0; r < 4; r++) oacc[nd][r] *= al;
    }
    lrun += ssum;

    // pack P tiles (B-operand == C-layout)
    bf16x4 pB[4];
#pragma unroll
    for (int nt = 0; nt < 4; nt++) {
      bf16x4 pk = {(__bf16)st[nt][0], (__bf16)st[nt][1],
                   (__bf16)st[nt][2], (__bf16)st[nt][3]};
      pB[nt] = pk;
    }

    // O^T += V^T P^T ; one 16B V frag feeds key-subtiles 2tp and 2tp+1
    __builtin_amdgcn_s_setprio(1);
#pragma unroll
    for (int tp = 0; tp < 2; tp++) {
      const int chv = (tp * 4 + quad) ^ (l15 & 7);
#pragma unroll
      for (int nd = 0; nd < 4; nd++) {
        bf16x8 v8 =
            *(const bf16x8*)(&Vs[cur][(nd * 16 + l15) * 64 + chv * 8]);
        bf16x4 vA0 = {v8[0], v8[1], v8[2], v8[3]};
        bf16x4 vA1 = {v8[4], v8[5], v8[6], v8[7]};
        oacc[nd] = mfma_pv(vA0, pB[2 * tp], oacc[nd]);
        oacc[nd] = mfma_pv(vA1, pB[2 * tp + 1], oacc[nd]);
      }
    }
    __builtin_amdgcn_s_setprio(0);

    __builtin_amdgcn_s_barrier();  // all waves done reading buf cur
  }

  // deferred cross-quad l reduction (once per strip instead of per chunk)
  lrun += __shfl_xor(lrun, 16, 64);
  lrun += __shfl_xor(lrun, 32, 64);

  // epilogue: direct normalize + store (no merge).
  const float linv = 1.0f / lrun;
#pragma unroll
  for (int nd = 0; nd < 4; nd++) {
    bf16x4 o = {(__bf16)(oacc[nd][0] * linv), (__bf16)(oacc[nd][1] * linv),
                (__bf16)(oacc[nd][2] * linv), (__bf16)(oacc[nd][3] * linv)};
    *(bf16x4*)(ctx + ((size_t)(b * 2048 + qrow)) * 1024 + h * 64 + nd * 16 +
               quad * 4) = o;
  }
}

// ---------------------------------------------------------------------------
extern "C" void kernel_launch(void* const* d_in, const int* in_sizes, int n_in,
                              void* d_out, int out_size, void* d_ws, size_t ws_size,
                              hipStream_t stream) {
  const float* x  = (const float*)d_in[0];
  const int*   am = (const int*)d_in[1];
  const float* Wq = (const float*)d_in[2];
  const float* bq = (const float*)d_in[3];
  const float* Aq = (const float*)d_in[4];
  const float* Bq = (const float*)d_in[5];
  const float* Wp = (const float*)d_in[6];
  const float* bp = (const float*)d_in[7];
  const float* Ap = (const float*)d_in[8];
  const float* Bp = (const float*)d_in[9];

  __bf16* wqkvT = (__bf16*)d_ws;                       // [3072][1024]
  __bf16* wpT   = wqkvT + (size_t)3072 * 1024;         // [1024][1024]
  __bf16* xbf   = wpT   + (size_t)1024 * 1024;         // [4096][1024]
  __bf16* qbuf  = xbf   + (size_t)4096 * 1024;         // [2][16][2048][64] (+kbuf)
  __bf16* vtbuf = qbuf  + (size_t)2 * 4194304;         // [2][16][64][2048] permuted
  __bf16* ctxb  = vtbuf + (size_t)4194304;             // [4096][1024]

  fold_wt2<<<dim3(64, 16), 256, 0, stream>>>(Wq, Aq, Bq, wqkvT,
                                             Wp, Ap, Bp, wpT);
  cast_x<<<4096, 256, 0, stream>>>(x, xbf);

  gemm_qkv<<<dim3(32, 24), 256, 0, stream>>>(wqkvT, xbf, bq, qbuf, vtbuf);
  flash_attn<<<1024, 256, 0, stream>>>(qbuf, qbuf + 4194304, vtbuf, am, ctxb);
  gemm_proj<<<dim3(8, 64), 256, 0, stream>>>(ctxb, wpT, bp, (float*)d_out, 1024);
}